// Round 1
// baseline (1237.411 us; speedup 1.0000x reference)
//
#include <hip/hip_runtime.h>

// GAE pipeline for MI355X. N=4096 nodes, E=65536 edges/view.
// Heavy GEMMs (GFN) use bf16-split MFMA (fp32-equivalent accuracy):
//   G1: h1 = relu(adjin @ W1^T + b1), adjin exact in bf16, W1 = W1h + W1l
//   G2: adj_r = h1 @ W2^T + b2, h1 = H1h + H1l, W2 = W2h + W2l (3 terms)
// Large scratch overlays d_out (regions are dead/alive in a safe order).

#define N_ 4096
#define E_ 65536

typedef __attribute__((ext_vector_type(8))) short short8;
typedef __attribute__((ext_vector_type(4))) float f32x4;

__device__ __forceinline__ float bf2f(unsigned short u) {
  union { unsigned int i; float f; } v; v.i = ((unsigned int)u) << 16; return v.f;
}
__device__ __forceinline__ unsigned short f2bf(float f) {
  union { float f; unsigned int i; } v; v.f = f;
  return (unsigned short)((v.i + 0x7fffu + ((v.i >> 16) & 1u)) >> 16);
}

// ----------------------------------------------------------------------------
// small kernels
// ----------------------------------------------------------------------------

__global__ void k_count(const int* __restrict__ s, const int* __restrict__ d,
                        float* __restrict__ dego, float* __restrict__ degi) {
  int e = blockIdx.x * 256 + threadIdx.x;
  if (e < E_) {
    atomicAdd(&dego[s[e]], 1.f);
    atomicAdd(&degi[d[e]], 1.f);
  }
}

__global__ void k_rsq(float* __restrict__ p, int n) {
  int i = blockIdx.x * 256 + threadIdx.x;
  if (i < n) p[i] = 1.f / sqrtf(fmaxf(p[i], 1.f));
}

__global__ void k_adjin(const float4* __restrict__ a, const float4* __restrict__ b,
                        const float4* __restrict__ c, ushort* __restrict__ o, int n4) {
  int i = blockIdx.x * 256 + threadIdx.x;
  if (i >= n4) return;
  float4 x = a[i], y = b[i], z = c[i];
  ushort4 r;
  r.x = f2bf(x.x + y.x + z.x);
  r.y = f2bf(x.y + y.y + z.y);
  r.z = f2bf(x.z + y.z + z.z);
  r.w = f2bf(x.w + y.w + z.w);
  *(ushort4*)(o + (size_t)i * 4) = r;
}

__global__ void k_split(const float4* __restrict__ w, ushort* __restrict__ hh,
                        ushort* __restrict__ hl, int n4) {
  int i = blockIdx.x * 256 + threadIdx.x;
  if (i >= n4) return;
  float4 x = w[i];
  ushort4 h, l;
  h.x = f2bf(x.x); l.x = f2bf(x.x - bf2f(h.x));
  h.y = f2bf(x.y); l.y = f2bf(x.y - bf2f(h.y));
  h.z = f2bf(x.z); l.z = f2bf(x.z - bf2f(h.z));
  h.w = f2bf(x.w); l.w = f2bf(x.w - bf2f(h.w));
  *(ushort4*)(hh + (size_t)i * 4) = h;
  *(ushort4*)(hl + (size_t)i * 4) = l;
}

template<int C>
__global__ void k_scatter(const int* __restrict__ s, const int* __restrict__ d,
                          const float* __restrict__ h, float* __restrict__ agg) {
  int t = blockIdx.x * 256 + threadIdx.x;
  int e = t / C, c = t % C;
  if (e < E_) atomicAdd(&agg[(size_t)d[e] * C + c], h[(size_t)s[e] * C + c]);
}

template<int RELU, int WT>
__global__ void k_finalize(const float* __restrict__ agg, const float* __restrict__ rs,
                           const float* __restrict__ bias, float* __restrict__ out,
                           float* __restrict__ outT, int C) {
  int i = blockIdx.x * 256 + threadIdx.x;
  int row = i / C, c = i % C;
  if (row >= N_) return;
  float v = agg[i] * rs[row] + bias[c];
  if (RELU) v = fmaxf(v, 0.f);
  out[i] = v;
  if (WT) outT[(size_t)c * N_ + row] = v;
}

// softmax over 64 cols; relu(softmax(x)) == softmax(x) since softmax > 0
__global__ void k_softmax(const float* __restrict__ zp, float* __restrict__ z) {
  int row = blockIdx.x * 4 + (threadIdx.x >> 6);
  int lane = threadIdx.x & 63;
  float v = zp[row * 64 + lane];
  float m = v;
  for (int o = 32; o; o >>= 1) m = fmaxf(m, __shfl_xor(m, o, 64));
  float e = expf(v - m);
  float s = e;
  for (int o = 32; o; o >>= 1) s += __shfl_xor(s, o, 64);
  z[row * 64 + lane] = e / s;
}

// A = ((p + p^T) != 0) + I, p = round(clip(adj_r,0,1)+0.1) (RNE matches jnp.round)
// also accumulates row sums into degA (zeroed beforehand)
__global__ void k_buildA(const float* __restrict__ adjr, ushort* __restrict__ Ab,
                         float* __restrict__ degA) {
  int bi = blockIdx.y, bj = blockIdx.x;
  __shared__ float t2[64][65];
  int t = threadIdx.x;
  for (int i = 0; i < 16; ++i) {
    int idx = t + i * 256, r = idx >> 6, c = idx & 63;
    t2[r][c] = adjr[(size_t)(bj * 64 + r) * N_ + bi * 64 + c];
  }
  __syncthreads();
  int w = t >> 6, lane = t & 63;
  for (int rr = 0; rr < 16; ++rr) {
    int r = w * 16 + rr;
    int gi = bi * 64 + r, gj = bj * 64 + lane;
    float p1 = rintf(fminf(fmaxf(adjr[(size_t)gi * N_ + gj], 0.f), 1.f) + 0.1f);
    float p2 = rintf(fminf(fmaxf(t2[lane][r], 0.f), 1.f) + 0.1f);
    float a = ((p1 + p2) != 0.f ? 1.f : 0.f) + (gi == gj ? 1.f : 0.f);
    Ab[(size_t)gi * N_ + gj] = f2bf(a);
    float s = a;
    for (int o = 32; o; o >>= 1) s += __shfl_xor(s, o, 64);
    if (lane == 0) atomicAdd(&degA[gi], s);
  }
}

// ----------------------------------------------------------------------------
// generic fp32 GEMM: C[M,N] = rowscale .* (A[M,K] @ B[K,N]); split-K via grid.z
// A row-major (f32 or bf16), B row-major. ATOM=1 -> atomicAdd into zeroed C.
// BM=64, BK=32, block=256. TM = BN/16.
// ----------------------------------------------------------------------------
template<int BN, int TM, int ABF16, int RS, int ATOM>
__global__ __launch_bounds__(256) void k_gemm(
    const void* __restrict__ Ap, int lda, const float* __restrict__ B, int ldb,
    float* __restrict__ C, int ldc, int K, const float* __restrict__ rs) {
  __shared__ float As[64][33];
  __shared__ float Bs[32][BN];
  const int t = threadIdx.x;
  const int bm = blockIdx.x << 6;
  const int bn = blockIdx.y * BN;
  const int Kc = K / gridDim.z;
  const int kbeg = blockIdx.z * Kc, kend = kbeg + Kc;
  const int cg = t % (BN / 4), rg = t / (BN / 4);
  float av[TM][4];
#pragma unroll
  for (int i = 0; i < TM; ++i)
    for (int j = 0; j < 4; ++j) av[i][j] = 0.f;
  for (int k0 = kbeg; k0 < kend; k0 += 32) {
    __syncthreads();
#pragma unroll
    for (int i = 0; i < 8; ++i) {
      int idx = t + (i << 8), r = idx >> 5, c = idx & 31;
      float v;
      if (ABF16) v = bf2f(((const ushort*)Ap)[(size_t)(bm + r) * lda + k0 + c]);
      else v = ((const float*)Ap)[(size_t)(bm + r) * lda + k0 + c];
      As[r][c] = v;
    }
#pragma unroll
    for (int i = 0; i < (BN >> 3); ++i) {
      int idx = t + (i << 8), r = idx / BN, c = idx % BN;
      Bs[r][c] = B[(size_t)(k0 + r) * ldb + bn + c];
    }
    __syncthreads();
#pragma unroll
    for (int k = 0; k < 32; ++k) {
      float b0 = Bs[k][(cg << 2) + 0], b1 = Bs[k][(cg << 2) + 1];
      float b2 = Bs[k][(cg << 2) + 2], b3 = Bs[k][(cg << 2) + 3];
#pragma unroll
      for (int i = 0; i < TM; ++i) {
        float a = As[rg * TM + i][k];
        av[i][0] = fmaf(a, b0, av[i][0]);
        av[i][1] = fmaf(a, b1, av[i][1]);
        av[i][2] = fmaf(a, b2, av[i][2]);
        av[i][3] = fmaf(a, b3, av[i][3]);
      }
    }
  }
#pragma unroll
  for (int i = 0; i < TM; ++i) {
    int gm = bm + rg * TM + i;
    float s = RS ? rs[gm] : 1.f;
#pragma unroll
    for (int j = 0; j < 4; ++j) {
      int gn = bn + (cg << 2) + j;
      float v = av[i][j] * s;
      if (ATOM) atomicAdd(&C[(size_t)gm * ldc + gn], v);
      else C[(size_t)gm * ldc + gn] = v;
    }
  }
}

// ----------------------------------------------------------------------------
// bf16-split MFMA GEMM. C[M,Nn] = sum of terms A_i[M,K] @ B_j[Nn,K]^T (NT form,
// both row-major, K fast). Terms: (A0,B0) [+ (A0,B1) if NB>1] [+ (A1,B0) if NA>1].
// 128x128 tile, BK=64, 4 waves, 16x16x32 bf16, XOR-swizzled LDS (slot ^= row&7).
// EPI=1: relu(acc+bias) -> bf16 hi/lo split outputs. EPI=2: fp32 acc+bias.
// ----------------------------------------------------------------------------
template<int NA, int NB, int EPI>
__global__ __launch_bounds__(256, 2) void k_mfma(
    const ushort* __restrict__ A0, const ushort* __restrict__ A1,
    const ushort* __restrict__ B0, const ushort* __restrict__ B1,
    const float* __restrict__ bias, float* __restrict__ Cf,
    ushort* __restrict__ Oh, ushort* __restrict__ Ol, int Nn, int K) {
  constexpr int NOPS = NA + NB;
  __shared__ __align__(16) ushort lds[NOPS * 8192];
  const int t = threadIdx.x, lane = t & 63;
  const int wave = t >> 6, wm = wave >> 1, wn = wave & 1;
  const int bm = blockIdx.y << 7, bn = blockIdx.x << 7;
  const int hi = lane >> 4, r16 = lane & 15, rx = r16 & 7;
  const int srow = t >> 3, sslot = t & 7;

  const ushort* gsrc[4];
  int rb[4];
  {
    int no = 0;
    gsrc[no] = A0; rb[no] = bm; no++;
    if (NA > 1) { gsrc[no] = A1; rb[no] = bm; no++; }
    gsrc[no] = B0; rb[no] = bn; no++;
    if (NB > 1) { gsrc[no] = B1; rb[no] = bn; no++; }
  }

  f32x4 acc[4][4];
#pragma unroll
  for (int i = 0; i < 4; ++i)
#pragma unroll
    for (int j = 0; j < 4; ++j)
#pragma unroll
      for (int r = 0; r < 4; ++r) acc[i][j][r] = 0.f;

  for (int kt = 0; kt < K; kt += 64) {
    short8 stg[NOPS][4];
#pragma unroll
    for (int op = 0; op < NOPS; ++op) {
#pragma unroll
      for (int i = 0; i < 4; ++i) {
        int row = (i << 5) + srow;  // 0..127
        stg[op][i] = *(const short8*)(gsrc[op] + (size_t)(rb[op] + row) * K + kt + (sslot << 3));
      }
    }
    __syncthreads();  // previous compute done reading LDS
#pragma unroll
    for (int op = 0; op < NOPS; ++op) {
#pragma unroll
      for (int i = 0; i < 4; ++i) {
        int row = (i << 5) + srow;
        *(short8*)(&lds[op * 8192 + row * 64 + ((sslot ^ (row & 7)) << 3)]) = stg[op][i];
      }
    }
    __syncthreads();
#pragma unroll
    for (int k0 = 0; k0 < 2; ++k0) {
      const int soff = (((k0 << 2) + hi) ^ rx) << 3;
      short8 af[NA][4], bf[NB][4];
#pragma unroll
      for (int mi = 0; mi < 4; ++mi) {
        int row = (wm << 6) + (mi << 4) + r16;
        af[0][mi] = *(const short8*)(&lds[row * 64 + soff]);
        if (NA > 1) af[1][mi] = *(const short8*)(&lds[8192 + row * 64 + soff]);
      }
#pragma unroll
      for (int ni = 0; ni < 4; ++ni) {
        int row = (wn << 6) + (ni << 4) + r16;
        bf[0][ni] = *(const short8*)(&lds[NA * 8192 + row * 64 + soff]);
        if (NB > 1) bf[1][ni] = *(const short8*)(&lds[(NA + 1) * 8192 + row * 64 + soff]);
      }
#pragma unroll
      for (int mi = 0; mi < 4; ++mi)
#pragma unroll
        for (int ni = 0; ni < 4; ++ni) {
          acc[mi][ni] = __builtin_amdgcn_mfma_f32_16x16x32_bf16(af[0][mi], bf[0][ni], acc[mi][ni], 0, 0, 0);
          if (NB > 1)
            acc[mi][ni] = __builtin_amdgcn_mfma_f32_16x16x32_bf16(af[0][mi], bf[1][ni], acc[mi][ni], 0, 0, 0);
          if (NA > 1)
            acc[mi][ni] = __builtin_amdgcn_mfma_f32_16x16x32_bf16(af[1][mi], bf[0][ni], acc[mi][ni], 0, 0, 0);
        }
    }
  }
  // epilogue; C/D layout: col = lane&15, row = (lane>>4)*4 + reg  [m89-verified]
#pragma unroll
  for (int mi = 0; mi < 4; ++mi)
#pragma unroll
    for (int ni = 0; ni < 4; ++ni) {
      const int gn = bn + (wn << 6) + (ni << 4) + r16;
      const float bv = bias[gn];
#pragma unroll
      for (int r2 = 0; r2 < 4; ++r2) {
        const int gm = bm + (wm << 6) + (mi << 4) + (hi << 2) + r2;
        float v = acc[mi][ni][r2] + bv;
        if (EPI == 1) {
          v = fmaxf(v, 0.f);
          ushort hh = f2bf(v);
          Oh[(size_t)gm * Nn + gn] = hh;
          Ol[(size_t)gm * Nn + gn] = f2bf(v - bf2f(hh));
        } else {
          Cf[(size_t)gm * Nn + gn] = v;
        }
      }
    }
}

// ----------------------------------------------------------------------------
extern "C" void kernel_launch(void* const* d_in, const int* in_sizes, int n_in,
                              void* d_out, int out_size, void* d_ws, size_t ws_size,
                              hipStream_t stream) {
  const float* data[3] = {(const float*)d_in[0], (const float*)d_in[1], (const float*)d_in[2]};
  const int D[3] = {512, 256, 128};
  const int* src[3] = {(const int*)d_in[3], (const int*)d_in[6], (const int*)d_in[9]};
  const int* dst[3] = {(const int*)d_in[4], (const int*)d_in[7], (const int*)d_in[10]};
  const float* adjv[3] = {(const float*)d_in[5], (const float*)d_in[8], (const float*)d_in[11]};
  const float* w0[3] = {(const float*)d_in[12], (const float*)d_in[16], (const float*)d_in[20]};
  const float* b0[3] = {(const float*)d_in[13], (const float*)d_in[17], (const float*)d_in[21]};
  const float* w1[3] = {(const float*)d_in[14], (const float*)d_in[18], (const float*)d_in[22]};
  const float* b1[3] = {(const float*)d_in[15], (const float*)d_in[19], (const float*)d_in[23]};
  const float* wm0 = (const float*)d_in[24];
  const float* bm0 = (const float*)d_in[25];
  const float* wm1 = (const float*)d_in[26];
  const float* bm1 = (const float*)d_in[27];
  const float* fw[3] = {(const float*)d_in[28], (const float*)d_in[29], (const float*)d_in[30]};
  const float* gw1 = (const float*)d_in[31];
  const float* gb1 = (const float*)d_in[32];
  const float* gw2 = (const float*)d_in[33];
  const float* gb2 = (const float*)d_in[34];

  float* outf = (float*)d_out;
  float* adj_r = outf;                       // output 0: [4096,4096]
  float* adj_rec = outf + 16777216;          // output 1: [4096,4096]
  float* feat = outf + 33554432;             // output 2: [4096,32]
  // scratch overlay in adj_r region (dead before G2 writes adj_r):
  ushort* w1h = (ushort*)outf;               // [2048,4096] bf16 hi
  ushort* w1l = w1h + 8388608;               // lo
  ushort* adjin = w1h + 16777216;            // [4096,4096] bf16
  // scratch overlay in adj_rec region (dead before final feat@featT):
  ushort* o1u = (ushort*)adj_rec;
  ushort* h1h = o1u;                         // [4096,2048] bf16 hi
  ushort* h1l = o1u + 8388608;
  ushort* w2h = o1u + 16777216;              // [4096,2048] bf16 hi
  ushort* w2l = o1u + 25165824;
  ushort* Ab = o1u;                          // A matrix bf16, after G2 (h1 dead)

  float* wsf = (float*)d_ws;
  float* dego[3] = {wsf, wsf + 8192, wsf + 16384};
  float* degi[3] = {wsf + 4096, wsf + 12288, wsf + 20480};
  float* degA = wsf + 24576;
  float* hbuf = wsf + 28672;                 // [4096,128]
  float* aggb = hbuf + 524288;               // [4096,128]
  float* hbuf2 = aggb + 524288;              // [4096,64]
  float* fv[3] = {hbuf2 + 262144, hbuf2 + 524288, hbuf2 + 786432};
  float* zpre = hbuf2 + 1048576;
  float* zb = zpre + 262144;
  float* featT = zb + 262144;                // [32,4096]

  // 1) degrees (counts include duplicate edges, per segment_sum semantics)
  hipMemsetAsync(wsf, 0, 28672 * sizeof(float), stream);
  for (int v = 0; v < 3; ++v)
    k_count<<<256, 256, 0, stream>>>(src[v], dst[v], dego[v], degi[v]);
  k_rsq<<<96, 256, 0, stream>>>(wsf, 24576);  // all 6 deg arrays -> rsqrt(clip(.,1))

  // 2) per-view 2-layer GraphConv stacks
  const int SPK0[3] = {4, 2, 1};
  for (int v = 0; v < 3; ++v) {
    hipMemsetAsync(hbuf, 0, 524288 * 4, stream);
    k_gemm<128, 8, 0, 1, 1><<<dim3(64, 1, SPK0[v]), 256, 0, stream>>>(
        data[v], D[v], w0[v], 128, hbuf, 128, D[v], dego[v]);
    hipMemsetAsync(aggb, 0, 524288 * 4, stream);
    k_scatter<128><<<32768, 256, 0, stream>>>(src[v], dst[v], hbuf, aggb);
    k_finalize<1, 0><<<2048, 256, 0, stream>>>(aggb, degi[v], b0[v], hbuf, nullptr, 128);
    hipMemsetAsync(hbuf2, 0, 262144 * 4, stream);
    k_gemm<64, 4, 0, 1, 1><<<dim3(64, 1, 1), 256, 0, stream>>>(
        hbuf, 128, w1[v], 64, hbuf2, 64, 128, dego[v]);
    hipMemsetAsync(aggb, 0, 262144 * 4, stream);
    k_scatter<64><<<16384, 256, 0, stream>>>(src[v], dst[v], hbuf2, aggb);
    k_finalize<0, 0><<<1024, 256, 0, stream>>>(aggb, degi[v], b1[v], fv[v], nullptr, 64);
  }

  // 3) fusion: z = softmax(f1@fw1 + f2@fw2 + f3@fw3)  (relu(softmax)=softmax)
  hipMemsetAsync(zpre, 0, 262144 * 4, stream);
  for (int v = 0; v < 3; ++v)
    k_gemm<64, 4, 0, 0, 1><<<dim3(64, 1, 1), 256, 0, stream>>>(
        fv[v], 64, fw[v], 64, zpre, 64, 64, nullptr);
  k_softmax<<<1024, 256, 0, stream>>>(zpre, zb);

  // 4) GFN prep: adjin bf16 (exact), split weights into bf16 hi/lo
  k_adjin<<<16384, 256, 0, stream>>>((const float4*)adjv[0], (const float4*)adjv[1],
                                     (const float4*)adjv[2], adjin, 4194304);
  k_split<<<8192, 256, 0, stream>>>((const float4*)gw1, w1h, w1l, 2097152);
  k_split<<<8192, 256, 0, stream>>>((const float4*)gw2, w2h, w2l, 2097152);

  // 5) G1: h1 = relu(adjin @ W1^T + b1) -> bf16 hi/lo.  G2: adj_r = h1 @ W2^T + b2
  k_mfma<1, 2, 1><<<dim3(16, 32), 256, 0, stream>>>(
      adjin, nullptr, w1h, w1l, gb1, nullptr, h1h, h1l, 2048, 4096);
  k_mfma<2, 2, 2><<<dim3(32, 32), 256, 0, stream>>>(
      h1h, h1l, w2h, w2l, gb2, adj_r, nullptr, nullptr, 4096, 2048);

  // 6) consensus graph A + degrees
  k_buildA<<<dim3(64, 64), 256, 0, stream>>>(adj_r, Ab, degA);
  k_rsq<<<16, 256, 0, stream>>>(degA, 4096);

  // 7) consensus GraphConv layer 0 (relu) and layer 1
  hipMemsetAsync(hbuf2, 0, 262144 * 4, stream);
  k_gemm<64, 4, 0, 1, 1><<<dim3(64, 1, 1), 256, 0, stream>>>(
      zb, 64, wm0, 64, hbuf2, 64, 64, degA);
  hipMemsetAsync(aggb, 0, 262144 * 4, stream);
  k_gemm<64, 4, 1, 0, 1><<<dim3(64, 1, 8), 256, 0, stream>>>(
      Ab, 4096, hbuf2, 64, aggb, 64, 4096, nullptr);
  k_finalize<1, 0><<<1024, 256, 0, stream>>>(aggb, degA, bm0, hbuf, nullptr, 64);

  hipMemsetAsync(hbuf2, 0, 131072 * 4, stream);
  k_gemm<32, 2, 0, 1, 1><<<dim3(64, 1, 1), 256, 0, stream>>>(
      hbuf, 64, wm1, 32, hbuf2, 32, 64, degA);
  hipMemsetAsync(aggb, 0, 131072 * 4, stream);
  k_gemm<32, 2, 1, 0, 1><<<dim3(64, 1, 8), 256, 0, stream>>>(
      Ab, 4096, hbuf2, 32, aggb, 32, 4096, nullptr);
  k_finalize<0, 1><<<512, 256, 0, stream>>>(aggb, degA, bm1, feat, featT, 32);

  // 8) adj_rec = feat @ feat^T
  k_gemm<128, 8, 0, 0, 0><<<dim3(64, 32, 1), 256, 0, stream>>>(
      feat, 32, featT, 4096, adj_rec, 4096, 32, nullptr);
}

// Round 2
// 1047.665 us; speedup vs baseline: 1.1811x; 1.1811x over previous
//
#include <hip/hip_runtime.h>

// GAE pipeline for MI355X. N=4096 nodes, E=65536 edges/view.
// Order: (a) GFN (bitmaps->adjin->G1->G2->buildA), (b) per-view stacks via
// CSR gather-agg + fusion, (c) consensus + adj_rec.
// Heavy GEMMs (GFN) use bf16-split MFMA with issue-early reg double-buffer.

#define N_ 4096
#define E_ 65536

typedef __attribute__((ext_vector_type(8))) short short8;
typedef __attribute__((ext_vector_type(4))) float f32x4;

__device__ __forceinline__ float bf2f(unsigned short u) {
  union { unsigned int i; float f; } v; v.i = ((unsigned int)u) << 16; return v.f;
}
__device__ __forceinline__ unsigned short f2bf(float f) {
  union { float f; unsigned int i; } v; v.f = f;
  return (unsigned short)((v.i + 0x7fffu + ((v.i >> 16) & 1u)) >> 16);
}

// ---------------------------------------------------------------------------
// ws layout (float offsets)
// ---------------------------------------------------------------------------
#define OFF_DEG    0         // dego/degi x3 (8192 each), degA @ 24576; 28672 total
#define OFF_HX     28672     // 4096x128 XW0 out          (bitmap region in (a))
#define OFF_HBUF   552960    // 4096x128 L0 result        (bitmap region in (a))
#define OFF_HBUF2  1077248   // 4096x64                   (bitmap region in (a))
#define OFF_FV1    1339392   // 4096x64 / aggc in (c)     (bitmap region in (a))
#define OFF_FV2    1601536   // 4096x64 / aggc2 in (c)
#define OFF_FV3    1863680   // 4096x64 / featT in (c)
#define OFF_ZB     2125824   // 4096x64
#define OFF_ZPRE   2387968   // 4096x64; CSR region in (b) before fusion
#define CSR_STRIDE 73732     // ints per view: ptr 4100, cur 4096, cidx 65536

// ---------------------------------------------------------------------------
// small kernels
// ---------------------------------------------------------------------------

__global__ void k_count3(const int* __restrict__ s1, const int* __restrict__ d1,
                         const int* __restrict__ s2, const int* __restrict__ d2,
                         const int* __restrict__ s3, const int* __restrict__ d3,
                         float* __restrict__ wd) {
  int v = blockIdx.x >> 8;
  int e = (blockIdx.x & 255) * 256 + threadIdx.x;
  const int* sv = v == 0 ? s1 : (v == 1 ? s2 : s3);
  const int* dv = v == 0 ? d1 : (v == 1 ? d2 : d3);
  atomicAdd(&wd[v * 8192 + sv[e]], 1.f);
  atomicAdd(&wd[v * 8192 + 4096 + dv[e]], 1.f);
}

__global__ void k_rsq(float* __restrict__ p, int n) {
  int i = blockIdx.x * 256 + threadIdx.x;
  if (i < n) p[i] = 1.f / sqrtf(fmaxf(p[i], 1.f));
}

// exclusive scan of degi (pre-rsqrt counts) -> ptr, zero cur. one block/view.
__global__ void k_scan(const float* __restrict__ wd, int* __restrict__ csr) {
  int v = blockIdx.x;
  const float* di = wd + v * 8192 + 4096;
  int* ptr = csr + v * CSR_STRIDE;
  int* cur = ptr + 4100;
  __shared__ int part[256];
  int t = threadIdx.x;
  int local[16];
  int s = 0;
#pragma unroll
  for (int i = 0; i < 16; ++i) { local[i] = s; s += (int)di[t * 16 + i]; }
  part[t] = s;
  __syncthreads();
  for (int o = 1; o < 256; o <<= 1) {
    int x = (t >= o) ? part[t - o] : 0;
    __syncthreads();
    part[t] += x;
    __syncthreads();
  }
  int base = (t > 0) ? part[t - 1] : 0;
#pragma unroll
  for (int i = 0; i < 16; ++i) { ptr[t * 16 + i] = base + local[i]; cur[t * 16 + i] = 0; }
  if (t == 255) ptr[4096] = part[255];
}

__global__ void k_fill(const int* __restrict__ s1, const int* __restrict__ d1,
                       const int* __restrict__ s2, const int* __restrict__ d2,
                       const int* __restrict__ s3, const int* __restrict__ d3,
                       int* __restrict__ csr) {
  int v = blockIdx.x >> 8;
  int e = (blockIdx.x & 255) * 256 + threadIdx.x;
  const int* sv = v == 0 ? s1 : (v == 1 ? s2 : s3);
  const int* dv = v == 0 ? d1 : (v == 1 ? d2 : d3);
  int* ptr = csr + v * CSR_STRIDE;
  int* cur = ptr + 4100;
  int* cidx = cur + 4096;
  int d = dv[e];
  int pos = ptr[d] + atomicAdd(&cur[d], 1);
  cidx[pos] = sv[e];
}

// gather-aggregate: out[dst] = relu?( (sum_{e in dst} h[src_e]) * rs[dst] + b )
template<int C, int RELU>
__global__ void k_agg(const float* __restrict__ h, const int* __restrict__ csrv,
                      const float* __restrict__ rs, const float* __restrict__ bias,
                      float* __restrict__ out) {
  const int* ptr = csrv;
  const int* cidx = csrv + 4100 + 4096;
  int wave = threadIdx.x >> 6, lane = threadIdx.x & 63;
  int dst, col;
  if (C == 128) { dst = (blockIdx.x << 1) + (wave >> 1); col = ((wave & 1) << 6) + lane; }
  else          { dst = (blockIdx.x << 2) + wave;        col = lane; }
  int e0 = ptr[dst], e1 = ptr[dst + 1];
  float acc = 0.f;
  for (int e = e0; e < e1; ++e) acc += h[(size_t)cidx[e] * C + col];
  float v = acc * rs[dst] + bias[col];
  if (RELU) v = fmaxf(v, 0.f);
  out[(size_t)dst * C + col] = v;
}

// set bit (s*4096+d) in per-view bitmap (dedupes within view, like np assign)
__global__ void k_bitset(const int* __restrict__ s1, const int* __restrict__ d1,
                         const int* __restrict__ s2, const int* __restrict__ d2,
                         const int* __restrict__ s3, const int* __restrict__ d3,
                         unsigned* __restrict__ bm) {
  int v = blockIdx.x >> 8;
  int e = (blockIdx.x & 255) * 256 + threadIdx.x;
  const int* sv = v == 0 ? s1 : (v == 1 ? s2 : s3);
  const int* dv = v == 0 ? d1 : (v == 1 ? d2 : d3);
  unsigned idx = (unsigned)sv[e] * 4096u + (unsigned)dv[e];
  atomicOr(&bm[v * 524288 + (idx >> 5)], 1u << (idx & 31));
}

// adjin bf16 from the 3 bitmaps; 8 entries/thread (16B store)
__global__ void k_b2a(const unsigned* __restrict__ bm, ushort* __restrict__ adjin) {
  int i = blockIdx.x * 256 + threadIdx.x;  // [0, 2097152)
  int w = i >> 2, sh = (i & 3) << 3;
  unsigned a = bm[w] >> sh, b = bm[524288 + w] >> sh, c = bm[1048576 + w] >> sh;
  short8 o;
#pragma unroll
  for (int k = 0; k < 8; ++k) {
    int cnt = ((a >> k) & 1) + ((b >> k) & 1) + ((c >> k) & 1);
    o[k] = (short)f2bf((float)cnt);
  }
  *(short8*)(adjin + (size_t)i * 8) = o;
}

// split gw1 [2048,4096] and gw2 [4096,2048] into bf16 hi/lo
__global__ void k_split2(const float4* __restrict__ g1, const float4* __restrict__ g2,
                         ushort* __restrict__ w1h, ushort* __restrict__ w1l,
                         ushort* __restrict__ w2h, ushort* __restrict__ w2l) {
  int i = blockIdx.x * 256 + threadIdx.x;  // [0, 4194304)
  int hf = i >= 2097152;
  int j = hf ? i - 2097152 : i;
  float4 x = hf ? g2[j] : g1[j];
  ushort* ph = hf ? w2h : w1h;
  ushort* pl = hf ? w2l : w1l;
  ushort4 h, l;
  h.x = f2bf(x.x); l.x = f2bf(x.x - bf2f(h.x));
  h.y = f2bf(x.y); l.y = f2bf(x.y - bf2f(h.y));
  h.z = f2bf(x.z); l.z = f2bf(x.z - bf2f(h.z));
  h.w = f2bf(x.w); l.w = f2bf(x.w - bf2f(h.w));
  *(ushort4*)(ph + (size_t)j * 4) = h;
  *(ushort4*)(pl + (size_t)j * 4) = l;
}

template<int RELU, int WT>
__global__ void k_finalize(const float* __restrict__ agg, const float* __restrict__ rs,
                           const float* __restrict__ bias, float* __restrict__ out,
                           float* __restrict__ outT, int C) {
  int i = blockIdx.x * 256 + threadIdx.x;
  int row = i / C, c = i % C;
  if (row >= N_) return;
  float v = agg[i] * rs[row] + bias[c];
  if (RELU) v = fmaxf(v, 0.f);
  out[i] = v;
  if (WT) outT[(size_t)c * N_ + row] = v;
}

__global__ void k_softmax(const float* __restrict__ zp, float* __restrict__ z) {
  int row = blockIdx.x * 4 + (threadIdx.x >> 6);
  int lane = threadIdx.x & 63;
  float v = zp[row * 64 + lane];
  float m = v;
  for (int o = 32; o; o >>= 1) m = fmaxf(m, __shfl_xor(m, o, 64));
  float e = expf(v - m);
  float s = e;
  for (int o = 32; o; o >>= 1) s += __shfl_xor(s, o, 64);
  z[row * 64 + lane] = e / s;
}

// A = ((p + p^T) != 0) + I, p = round(clip(adj_r,0,1)+0.1); rowsum -> degA
__global__ void k_buildA(const float* __restrict__ adjr, ushort* __restrict__ Ab,
                         float* __restrict__ degA) {
  int bi = blockIdx.y, bj = blockIdx.x;
  __shared__ float t2[64][65];
  int t = threadIdx.x;
  for (int i = 0; i < 16; ++i) {
    int idx = t + i * 256, r = idx >> 6, c = idx & 63;
    t2[r][c] = adjr[(size_t)(bj * 64 + r) * N_ + bi * 64 + c];
  }
  __syncthreads();
  int w = t >> 6, lane = t & 63;
  for (int rr = 0; rr < 16; ++rr) {
    int r = w * 16 + rr;
    int gi = bi * 64 + r, gj = bj * 64 + lane;
    float p1 = rintf(fminf(fmaxf(adjr[(size_t)gi * N_ + gj], 0.f), 1.f) + 0.1f);
    float p2 = rintf(fminf(fmaxf(t2[lane][r], 0.f), 1.f) + 0.1f);
    float a = ((p1 + p2) != 0.f ? 1.f : 0.f) + (gi == gj ? 1.f : 0.f);
    Ab[(size_t)gi * N_ + gj] = f2bf(a);
    float s = a;
    for (int o = 32; o; o >>= 1) s += __shfl_xor(s, o, 64);
    if (lane == 0) atomicAdd(&degA[gi], s);
  }
}

// ---------------------------------------------------------------------------
// generic fp32 GEMM: C[M,N] = rowscale .* (A[M,K] @ B[K,N]); BM=64, BK=32.
// ---------------------------------------------------------------------------
template<int BN, int TM, int ABF16, int RS, int ATOM>
__global__ __launch_bounds__(256) void k_gemm(
    const void* __restrict__ Ap, int lda, const float* __restrict__ B, int ldb,
    float* __restrict__ C, int ldc, int K, const float* __restrict__ rs) {
  __shared__ float As[64][33];
  __shared__ float Bs[32][BN];
  const int t = threadIdx.x;
  const int bm = blockIdx.x << 6;
  const int bn = blockIdx.y * BN;
  const int Kc = K / gridDim.z;
  const int kbeg = blockIdx.z * Kc, kend = kbeg + Kc;
  const int cg = t % (BN / 4), rg = t / (BN / 4);
  float av[TM][4];
#pragma unroll
  for (int i = 0; i < TM; ++i)
#pragma unroll
    for (int j = 0; j < 4; ++j) av[i][j] = 0.f;
  for (int k0 = kbeg; k0 < kend; k0 += 32) {
    __syncthreads();
#pragma unroll
    for (int i = 0; i < 8; ++i) {
      int idx = t + (i << 8), r = idx >> 5, c = idx & 31;
      float v;
      if (ABF16) v = bf2f(((const ushort*)Ap)[(size_t)(bm + r) * lda + k0 + c]);
      else v = ((const float*)Ap)[(size_t)(bm + r) * lda + k0 + c];
      As[r][c] = v;
    }
#pragma unroll
    for (int i = 0; i < (BN >> 3); ++i) {
      int idx = t + (i << 8), r = idx / BN, c = idx % BN;
      Bs[r][c] = B[(size_t)(k0 + r) * ldb + bn + c];
    }
    __syncthreads();
#pragma unroll
    for (int k = 0; k < 32; ++k) {
      float b0 = Bs[k][(cg << 2) + 0], b1 = Bs[k][(cg << 2) + 1];
      float b2 = Bs[k][(cg << 2) + 2], b3 = Bs[k][(cg << 2) + 3];
#pragma unroll
      for (int i = 0; i < TM; ++i) {
        float a = As[rg * TM + i][k];
        av[i][0] = fmaf(a, b0, av[i][0]);
        av[i][1] = fmaf(a, b1, av[i][1]);
        av[i][2] = fmaf(a, b2, av[i][2]);
        av[i][3] = fmaf(a, b3, av[i][3]);
      }
    }
  }
#pragma unroll
  for (int i = 0; i < TM; ++i) {
    int gm = bm + rg * TM + i;
    float s = RS ? rs[gm] : 1.f;
#pragma unroll
    for (int j = 0; j < 4; ++j) {
      int gn = bn + (cg << 2) + j;
      float v = av[i][j] * s;
      if (ATOM) atomicAdd(&C[(size_t)gm * ldc + gn], v);
      else C[(size_t)gm * ldc + gn] = v;
    }
  }
}

// ---------------------------------------------------------------------------
// bf16-split MFMA GEMM, 128x128 tile, BK=64, 4 waves, XOR-swizzled LDS.
// Issue-early register double-buffer: next tile's global loads are issued
// right after barrier-2 so they fly during the MFMA phase.
// ---------------------------------------------------------------------------
template<int NA, int NB, int EPI>
__global__ __launch_bounds__(256, 2) void k_mfma(
    const ushort* __restrict__ A0, const ushort* __restrict__ A1,
    const ushort* __restrict__ B0, const ushort* __restrict__ B1,
    const float* __restrict__ bias, float* __restrict__ Cf,
    ushort* __restrict__ Oh, ushort* __restrict__ Ol, int Nn, int K) {
  constexpr int NOPS = NA + NB;
  __shared__ __align__(16) ushort lds[NOPS * 8192];
  const int t = threadIdx.x, lane = t & 63;
  const int wave = t >> 6, wm = wave >> 1, wn = wave & 1;
  const int bm = blockIdx.y << 7, bn = blockIdx.x << 7;
  const int hi = lane >> 4, r16 = lane & 15, rx = r16 & 7;
  const int srow = t >> 3, sslot = t & 7;

  const ushort* gsrc[4];
  int rb[4];
  {
    int no = 0;
    gsrc[no] = A0; rb[no] = bm; no++;
    if (NA > 1) { gsrc[no] = A1; rb[no] = bm; no++; }
    gsrc[no] = B0; rb[no] = bn; no++;
    if (NB > 1) { gsrc[no] = B1; rb[no] = bn; no++; }
  }

  f32x4 acc[4][4];
#pragma unroll
  for (int i = 0; i < 4; ++i)
#pragma unroll
    for (int j = 0; j < 4; ++j)
#pragma unroll
      for (int r = 0; r < 4; ++r) acc[i][j][r] = 0.f;

  short8 stg[NOPS][4];
#define LOADT(KT)                                                                      \
  {                                                                                    \
    _Pragma("unroll") for (int op = 0; op < NOPS; ++op)                                \
        _Pragma("unroll") for (int i = 0; i < 4; ++i) {                                \
      int row = (i << 5) + srow;                                                       \
      stg[op][i] = *(const short8*)(gsrc[op] + (size_t)(rb[op] + row) * K + (KT) +     \
                                    (sslot << 3));                                     \
    }                                                                                  \
  }

  LOADT(0);
  for (int kt = 0; kt < K; kt += 64) {
    __syncthreads();  // all waves done reading LDS of previous tile
#pragma unroll
    for (int op = 0; op < NOPS; ++op)
#pragma unroll
      for (int i = 0; i < 4; ++i) {
        int row = (i << 5) + srow;
        *(short8*)(&lds[op * 8192 + row * 64 + ((sslot ^ (row & 7)) << 3)]) = stg[op][i];
      }
    __syncthreads();
    if (kt + 64 < K) LOADT(kt + 64);  // in flight during compute below
#pragma unroll
    for (int k0 = 0; k0 < 2; ++k0) {
      const int soff = (((k0 << 2) + hi) ^ rx) << 3;
      short8 af[NA][4], bf[NB][4];
#pragma unroll
      for (int mi = 0; mi < 4; ++mi) {
        int row = (wm << 6) + (mi << 4) + r16;
        af[0][mi] = *(const short8*)(&lds[row * 64 + soff]);
        if (NA > 1) af[1][mi] = *(const short8*)(&lds[8192 + row * 64 + soff]);
      }
#pragma unroll
      for (int ni = 0; ni < 4; ++ni) {
        int row = (wn << 6) + (ni << 4) + r16;
        bf[0][ni] = *(const short8*)(&lds[NA * 8192 + row * 64 + soff]);
        if (NB > 1) bf[1][ni] = *(const short8*)(&lds[(NA + 1) * 8192 + row * 64 + soff]);
      }
#pragma unroll
      for (int mi = 0; mi < 4; ++mi)
#pragma unroll
        for (int ni = 0; ni < 4; ++ni) {
          acc[mi][ni] = __builtin_amdgcn_mfma_f32_16x16x32_bf16(af[0][mi], bf[0][ni], acc[mi][ni], 0, 0, 0);
          if (NB > 1)
            acc[mi][ni] = __builtin_amdgcn_mfma_f32_16x16x32_bf16(af[0][mi], bf[1][ni], acc[mi][ni], 0, 0, 0);
          if (NA > 1)
            acc[mi][ni] = __builtin_amdgcn_mfma_f32_16x16x32_bf16(af[1][mi], bf[0][ni], acc[mi][ni], 0, 0, 0);
        }
    }
  }
  // epilogue; C/D layout: col = lane&15, row = (lane>>4)*4 + reg
#pragma unroll
  for (int mi = 0; mi < 4; ++mi)
#pragma unroll
    for (int ni = 0; ni < 4; ++ni) {
      const int gn = bn + (wn << 6) + (ni << 4) + r16;
      const float bv = bias[gn];
#pragma unroll
      for (int r2 = 0; r2 < 4; ++r2) {
        const int gm = bm + (wm << 6) + (mi << 4) + (hi << 2) + r2;
        float v = acc[mi][ni][r2] + bv;
        if (EPI == 1) {
          v = fmaxf(v, 0.f);
          ushort hh = f2bf(v);
          Oh[(size_t)gm * Nn + gn] = hh;
          Ol[(size_t)gm * Nn + gn] = f2bf(v - bf2f(hh));
        } else {
          Cf[(size_t)gm * Nn + gn] = v;
        }
      }
    }
}

// ---------------------------------------------------------------------------
extern "C" void kernel_launch(void* const* d_in, const int* in_sizes, int n_in,
                              void* d_out, int out_size, void* d_ws, size_t ws_size,
                              hipStream_t stream) {
  const float* data[3] = {(const float*)d_in[0], (const float*)d_in[1], (const float*)d_in[2]};
  const int D[3] = {512, 256, 128};
  const int* src[3] = {(const int*)d_in[3], (const int*)d_in[6], (const int*)d_in[9]};
  const int* dst[3] = {(const int*)d_in[4], (const int*)d_in[7], (const int*)d_in[10]};
  const float* w0[3] = {(const float*)d_in[12], (const float*)d_in[16], (const float*)d_in[20]};
  const float* b0[3] = {(const float*)d_in[13], (const float*)d_in[17], (const float*)d_in[21]};
  const float* w1[3] = {(const float*)d_in[14], (const float*)d_in[18], (const float*)d_in[22]};
  const float* b1[3] = {(const float*)d_in[15], (const float*)d_in[19], (const float*)d_in[23]};
  const float* wm0 = (const float*)d_in[24];
  const float* bm0 = (const float*)d_in[25];
  const float* wm1 = (const float*)d_in[26];
  const float* bm1 = (const float*)d_in[27];
  const float* fw[3] = {(const float*)d_in[28], (const float*)d_in[29], (const float*)d_in[30]};
  const float* gw1 = (const float*)d_in[31];
  const float* gb1 = (const float*)d_in[32];
  const float* gw2 = (const float*)d_in[33];
  const float* gb2 = (const float*)d_in[34];

  float* outf = (float*)d_out;
  float* adj_r = outf;                  // output 0
  float* adj_rec = outf + 16777216;     // output 1
  float* feat = outf + 33554432;        // output 2
  // adj_r region overlay (dead before G2 writes adj_r):
  ushort* w1h = (ushort*)outf;          // [2048,4096]
  ushort* w1l = w1h + 8388608;
  ushort* adjin = w1h + 16777216;       // [4096,4096]
  // adj_rec region overlay (dead before final feat@featT):
  ushort* o1u = (ushort*)adj_rec;
  ushort* h1h = o1u;                    // [4096,2048]
  ushort* h1l = o1u + 8388608;
  ushort* w2h = o1u + 16777216;         // [4096,2048]
  ushort* w2l = o1u + 25165824;
  ushort* Ab = o1u;                     // A bf16, after G2 (h1 dead)

  float* wsf = (float*)d_ws;
  float* degA = wsf + 24576;
  float* hX = wsf + OFF_HX;
  float* hbuf = wsf + OFF_HBUF;
  float* hbuf2 = wsf + OFF_HBUF2;
  float* fv[3] = {wsf + OFF_FV1, wsf + OFF_FV2, wsf + OFF_FV3};
  float* zb = wsf + OFF_ZB;
  float* zpre = wsf + OFF_ZPRE;
  int* csr = (int*)(wsf + OFF_ZPRE);
  unsigned* bm = (unsigned*)(wsf + OFF_HX);   // 3 x 2MB bitmaps (phase a only)
  float* aggc = wsf + OFF_FV1;                // phase c
  float* aggc2 = wsf + OFF_FV2;
  float* featT = wsf + OFF_FV3;

  // ---- phase (a): GFN first (bitmaps reuse the per-view ws regions) ----
  hipMemsetAsync(wsf, 0, (size_t)1601536 * 4, stream);  // deg + degA + bitmaps
  k_bitset<<<768, 256, 0, stream>>>(src[0], dst[0], src[1], dst[1], src[2], dst[2], bm);
  k_b2a<<<8192, 256, 0, stream>>>(bm, adjin);
  k_split2<<<16384, 256, 0, stream>>>((const float4*)gw1, (const float4*)gw2, w1h, w1l, w2h, w2l);
  k_mfma<1, 2, 1><<<dim3(16, 32), 256, 0, stream>>>(
      adjin, nullptr, w1h, w1l, gb1, nullptr, h1h, h1l, 2048, 4096);
  k_mfma<2, 2, 2><<<dim3(32, 32), 256, 0, stream>>>(
      h1h, h1l, w2h, w2l, gb2, adj_r, nullptr, nullptr, 4096, 2048);
  k_buildA<<<dim3(64, 64), 256, 0, stream>>>(adj_r, Ab, degA);

  // ---- phase (b): per-view stacks via CSR + fusion ----
  k_count3<<<768, 256, 0, stream>>>(src[0], dst[0], src[1], dst[1], src[2], dst[2], wsf);
  k_scan<<<3, 256, 0, stream>>>(wsf, csr);
  k_rsq<<<112, 256, 0, stream>>>(wsf, 28672);  // all deg arrays + degA
  k_fill<<<768, 256, 0, stream>>>(src[0], dst[0], src[1], dst[1], src[2], dst[2], csr);

  for (int v = 0; v < 3; ++v) {
    const float* rso = wsf + v * 8192;
    const float* rsi = wsf + v * 8192 + 4096;
    const int* csrv = csr + v * CSR_STRIDE;
    k_gemm<32, 2, 0, 1, 0><<<dim3(64, 4, 1), 256, 0, stream>>>(
        data[v], D[v], w0[v], 128, hX, 128, D[v], rso);
    k_agg<128, 1><<<2048, 256, 0, stream>>>(hX, csrv, rsi, b0[v], hbuf);
    k_gemm<32, 2, 0, 1, 0><<<dim3(64, 2, 1), 256, 0, stream>>>(
        hbuf, 128, w1[v], 64, hbuf2, 64, 128, rso);
    k_agg<64, 0><<<1024, 256, 0, stream>>>(hbuf2, csrv, rsi, b1[v], fv[v]);
  }
  k_gemm<32, 2, 0, 0, 0><<<dim3(64, 2, 1), 256, 0, stream>>>(
      fv[0], 64, fw[0], 64, zpre, 64, 64, nullptr);
  k_gemm<32, 2, 0, 0, 1><<<dim3(64, 2, 1), 256, 0, stream>>>(
      fv[1], 64, fw[1], 64, zpre, 64, 64, nullptr);
  k_gemm<32, 2, 0, 0, 1><<<dim3(64, 2, 1), 256, 0, stream>>>(
      fv[2], 64, fw[2], 64, zpre, 64, 64, nullptr);
  k_softmax<<<1024, 256, 0, stream>>>(zpre, zb);

  // ---- phase (c): consensus GraphConvs + adj_rec ----
  k_gemm<32, 2, 0, 1, 0><<<dim3(64, 2, 1), 256, 0, stream>>>(
      zb, 64, wm0, 64, hbuf2, 64, 64, degA);
  hipMemsetAsync(aggc, 0, (size_t)393216 * 4, stream);  // aggc + aggc2
  k_gemm<64, 4, 1, 0, 1><<<dim3(64, 1, 8), 256, 0, stream>>>(
      Ab, 4096, hbuf2, 64, aggc, 64, 4096, nullptr);
  k_finalize<1, 0><<<1024, 256, 0, stream>>>(aggc, degA, bm0, hbuf, nullptr, 64);
  k_gemm<32, 2, 0, 1, 0><<<dim3(64, 1, 1), 256, 0, stream>>>(
      hbuf, 64, wm1, 32, hbuf2, 32, 64, degA);
  k_gemm<32, 2, 1, 0, 1><<<dim3(64, 1, 8), 256, 0, stream>>>(
      Ab, 4096, hbuf2, 32, aggc2, 32, 4096, nullptr);
  k_finalize<0, 1><<<512, 256, 0, stream>>>(aggc2, degA, bm1, feat, featT, 32);
  k_gemm<128, 8, 0, 0, 0><<<dim3(64, 32, 1), 256, 0, stream>>>(
      feat, 32, featT, 4096, adj_rec, 4096, 32, nullptr);
}

// Round 3
// 952.090 us; speedup vs baseline: 1.2997x; 1.1004x over previous
//
#include <hip/hip_runtime.h>

// GAE pipeline for MI355X. N=4096 nodes, E=65536 edges/view.
// Phase a: edges->bitmaps->adjin, weight splits, G1/G2 (bf16-split MFMA), buildA.
// Phase b: CSR build, per-view GraphConv stacks (fp32 gemm + gather-agg), fusion.
// Phase c: consensus GraphConvs via MFMA A@h (split-K partials), adj_rec.

#define N_ 4096
#define E_ 65536
#define CSR_STRIDE 73732  // ints per view: ptr 4100, cur 4096, cidx 65536

typedef __attribute__((ext_vector_type(8))) short short8;
typedef __attribute__((ext_vector_type(4))) float f32x4;

__device__ __forceinline__ float bf2f(unsigned short u) {
  union { unsigned int i; float f; } v; v.i = ((unsigned int)u) << 16; return v.f;
}
__device__ __forceinline__ unsigned short f2bf(float f) {
  union { float f; unsigned int i; } v; v.f = f;
  return (unsigned short)((v.i + 0x7fffu + ((v.i >> 16) & 1u)) >> 16);
}

// ---------------------------------------------------------------------------
// edge pass: degree counts + per-view dedupe bitmaps
// ---------------------------------------------------------------------------
__global__ void k_edges(const int* __restrict__ s1, const int* __restrict__ d1,
                        const int* __restrict__ s2, const int* __restrict__ d2,
                        const int* __restrict__ s3, const int* __restrict__ d3,
                        float* __restrict__ wd, unsigned* __restrict__ bmp) {
  int v = blockIdx.x >> 8;
  int e = (blockIdx.x & 255) * 256 + threadIdx.x;
  const int* sv = v == 0 ? s1 : (v == 1 ? s2 : s3);
  const int* dv = v == 0 ? d1 : (v == 1 ? d2 : d3);
  int s = sv[e], d = dv[e];
  atomicAdd(&wd[v * 8192 + s], 1.f);
  atomicAdd(&wd[v * 8192 + 4096 + d], 1.f);
  unsigned idx = (unsigned)s * 4096u + (unsigned)d;
  atomicOr(&bmp[v * 524288 + (idx >> 5)], 1u << (idx & 31));
}

// bitmaps -> adjin bf16, and split gw1/gw2 into bf16 hi/lo (one launch)
__global__ void k_prep(const unsigned* __restrict__ bmp, ushort* __restrict__ adjin,
                       const float4* __restrict__ g1, const float4* __restrict__ g2,
                       ushort* __restrict__ w1h, ushort* __restrict__ w1l,
                       ushort* __restrict__ w2h, ushort* __restrict__ w2l) {
  int i = blockIdx.x * 256 + threadIdx.x;
  if (i < 2097152) {
    int w = i >> 2, sh = (i & 3) << 3;
    unsigned a = bmp[w] >> sh, b = bmp[524288 + w] >> sh, c = bmp[1048576 + w] >> sh;
    short8 o;
#pragma unroll
    for (int k = 0; k < 8; ++k) {
      int cnt = ((a >> k) & 1) + ((b >> k) & 1) + ((c >> k) & 1);
      o[k] = (short)f2bf((float)cnt);
    }
    *(short8*)(adjin + (size_t)i * 8) = o;
  } else {
    int i2 = i - 2097152;
    int hf = i2 >= 2097152;
    int j = i2 & 2097151;
    float4 x = hf ? g2[j] : g1[j];
    ushort* ph = hf ? w2h : w1h;
    ushort* pl = hf ? w2l : w1l;
    ushort4 h, l;
    h.x = f2bf(x.x); l.x = f2bf(x.x - bf2f(h.x));
    h.y = f2bf(x.y); l.y = f2bf(x.y - bf2f(h.y));
    h.z = f2bf(x.z); l.z = f2bf(x.z - bf2f(h.z));
    h.w = f2bf(x.w); l.w = f2bf(x.w - bf2f(h.w));
    *(ushort4*)(ph + (size_t)j * 4) = h;
    *(ushort4*)(pl + (size_t)j * 4) = l;
  }
}

// blocks 0-2: CSR scan per view (+ rsqrt degi); blocks 3-5: rsqrt dego; 6: degA
__global__ void k_scan7(float* __restrict__ wd, int* __restrict__ csr) {
  int b = blockIdx.x, t = threadIdx.x;
  if (b < 3) {
    float* di = wd + b * 8192 + 4096;
    int* ptr = csr + b * CSR_STRIDE;
    int* cur = ptr + 4100;
    __shared__ int part[256];
    int local[16];
    float cnt[16];
    int s = 0;
#pragma unroll
    for (int i = 0; i < 16; ++i) { cnt[i] = di[t * 16 + i]; local[i] = s; s += (int)cnt[i]; }
    part[t] = s;
    __syncthreads();
    for (int o = 1; o < 256; o <<= 1) {
      int x = (t >= o) ? part[t - o] : 0;
      __syncthreads();
      part[t] += x;
      __syncthreads();
    }
    int base = (t > 0) ? part[t - 1] : 0;
#pragma unroll
    for (int i = 0; i < 16; ++i) {
      ptr[t * 16 + i] = base + local[i];
      cur[t * 16 + i] = 0;
      di[t * 16 + i] = 1.f / sqrtf(fmaxf(cnt[i], 1.f));
    }
    if (t == 255) ptr[4096] = part[255];
  } else {
    int off = (b == 3) ? 0 : (b == 4) ? 8192 : (b == 5) ? 16384 : 24576;
#pragma unroll
    for (int i = 0; i < 16; ++i) {
      int idx = off + t * 16 + i;
      wd[idx] = 1.f / sqrtf(fmaxf(wd[idx], 1.f));
    }
  }
}

__global__ void k_fill(const int* __restrict__ s1, const int* __restrict__ d1,
                       const int* __restrict__ s2, const int* __restrict__ d2,
                       const int* __restrict__ s3, const int* __restrict__ d3,
                       int* __restrict__ csr) {
  int v = blockIdx.x >> 8;
  int e = (blockIdx.x & 255) * 256 + threadIdx.x;
  const int* sv = v == 0 ? s1 : (v == 1 ? s2 : s3);
  const int* dv = v == 0 ? d1 : (v == 1 ? d2 : d3);
  int* ptr = csr + v * CSR_STRIDE;
  int* cur = ptr + 4100;
  int* cidx = cur + 4096;
  int d = dv[e];
  int pos = ptr[d] + atomicAdd(&cur[d], 1);
  cidx[pos] = sv[e];
}

// gather-aggregate: out[dst*os+oo+col] = relu?((sum h[src]) * rs[dst] + b[col])
template<int C, int RELU>
__global__ void k_agg(const float* __restrict__ h, const int* __restrict__ csrv,
                      const float* __restrict__ rs, const float* __restrict__ bias,
                      float* __restrict__ out, int os, int oo) {
  const int* ptr = csrv;
  const int* cidx = csrv + 4100 + 4096;
  int wave = threadIdx.x >> 6, lane = threadIdx.x & 63;
  int dst, col;
  if (C == 128) { dst = (blockIdx.x << 1) + (wave >> 1); col = ((wave & 1) << 6) + lane; }
  else          { dst = (blockIdx.x << 2) + wave;        col = lane; }
  int e0 = ptr[dst], e1 = ptr[dst + 1];
  float acc = 0.f;
  for (int e = e0; e < e1; ++e) acc += h[(size_t)cidx[e] * C + col];
  float v = acc * rs[dst] + bias[col];
  if (RELU) v = fmaxf(v, 0.f);
  out[(size_t)dst * os + oo + col] = v;
}

__global__ void k_softmax(const float* __restrict__ zp, float* __restrict__ z) {
  int row = blockIdx.x * 4 + (threadIdx.x >> 6);
  int lane = threadIdx.x & 63;
  float v = zp[row * 64 + lane];
  float m = v;
  for (int o = 32; o; o >>= 1) m = fmaxf(m, __shfl_xor(m, o, 64));
  float e = expf(v - m);
  float s = e;
  for (int o = 32; o; o >>= 1) s += __shfl_xor(s, o, 64);
  z[row * 64 + lane] = e / s;
}

// A = ((p + p^T) != 0) + I symmetric; pair-block version: block (bi<=bj) reads
// tiles (bi,bj) and (bj,bi) once, writes both A tiles, row+col sums -> degA
__global__ void k_buildA(const float* __restrict__ adjr, ushort* __restrict__ Ab,
                         float* __restrict__ degA) {
  int bi = blockIdx.y, bj = blockIdx.x;
  if (bi > bj) return;
  __shared__ float t2[64][65];
  __shared__ ushort at[64][65];
  __shared__ float cs[64];
  int t = threadIdx.x, w = t >> 6, lane = t & 63;
#pragma unroll
  for (int i = 0; i < 16; ++i) {
    int idx = t + i * 256, r = idx >> 6, c = idx & 63;
    t2[r][c] = adjr[(size_t)(bj * 64 + r) * N_ + bi * 64 + c];
  }
  if (t < 64) cs[t] = 0.f;
  __syncthreads();
  float colp = 0.f;
  for (int rr = 0; rr < 16; ++rr) {
    int r = w * 16 + rr;
    int gi = bi * 64 + r, gj = bj * 64 + lane;
    float p1 = rintf(fminf(fmaxf(adjr[(size_t)gi * N_ + gj], 0.f), 1.f) + 0.1f);
    float p2 = rintf(fminf(fmaxf(t2[lane][r], 0.f), 1.f) + 0.1f);
    float a = ((p1 + p2) != 0.f ? 1.f : 0.f) + (gi == gj ? 1.f : 0.f);
    ushort ab = f2bf(a);
    Ab[(size_t)gi * N_ + gj] = ab;
    at[lane][r] = ab;
    colp += a;
    float s = a;
    for (int o = 32; o; o >>= 1) s += __shfl_xor(s, o, 64);
    if (lane == 0) atomicAdd(&degA[gi], s);
  }
  if (bi < bj) {
    atomicAdd(&cs[lane], colp);
    __syncthreads();
#pragma unroll
    for (int i = 0; i < 16; ++i) {
      int idx = t + i * 256, r = idx >> 6, c = idx & 63;
      Ab[(size_t)(bj * 64 + r) * N_ + bi * 64 + c] = at[r][c];
    }
    if (t < 64) atomicAdd(&degA[bj * 64 + t], cs[t]);
  }
}

// ---------------------------------------------------------------------------
// generic fp32 GEMM: C[M,N] = rowscale .* (A[M,K] @ B[K,N]); BM=64, BK=32.
// ---------------------------------------------------------------------------
template<int BN, int TM, int RS>
__global__ __launch_bounds__(256) void k_gemm(
    const float* __restrict__ Ap, int lda, const float* __restrict__ B, int ldb,
    float* __restrict__ C, int ldc, int K, const float* __restrict__ rs) {
  __shared__ float As[64][33];
  __shared__ float Bs[32][BN];
  const int t = threadIdx.x;
  const int bm = blockIdx.x << 6;
  const int bn = blockIdx.y * BN;
  const int cg = t % (BN / 4), rg = t / (BN / 4);
  float av[TM][4];
#pragma unroll
  for (int i = 0; i < TM; ++i)
#pragma unroll
    for (int j = 0; j < 4; ++j) av[i][j] = 0.f;
  for (int k0 = 0; k0 < K; k0 += 32) {
    __syncthreads();
#pragma unroll
    for (int i = 0; i < 8; ++i) {
      int idx = t + (i << 8), r = idx >> 5, c = idx & 31;
      As[r][c] = Ap[(size_t)(bm + r) * lda + k0 + c];
    }
#pragma unroll
    for (int i = 0; i < (BN >> 3); ++i) {
      int idx = t + (i << 8), r = idx / BN, c = idx % BN;
      Bs[r][c] = B[(size_t)(k0 + r) * ldb + bn + c];
    }
    __syncthreads();
#pragma unroll
    for (int k = 0; k < 32; ++k) {
      float b0 = Bs[k][(cg << 2) + 0], b1 = Bs[k][(cg << 2) + 1];
      float b2 = Bs[k][(cg << 2) + 2], b3 = Bs[k][(cg << 2) + 3];
#pragma unroll
      for (int i = 0; i < TM; ++i) {
        float a = As[rg * TM + i][k];
        av[i][0] = fmaf(a, b0, av[i][0]);
        av[i][1] = fmaf(a, b1, av[i][1]);
        av[i][2] = fmaf(a, b2, av[i][2]);
        av[i][3] = fmaf(a, b3, av[i][3]);
      }
    }
  }
#pragma unroll
  for (int i = 0; i < TM; ++i) {
    int gm = bm + rg * TM + i;
    float s = RS ? rs[gm] : 1.f;
#pragma unroll
    for (int j = 0; j < 4; ++j)
      C[(size_t)gm * ldc + bn + (cg << 2) + j] = av[i][j] * s;
  }
}

// fusion GEMM: zpre = fvI[4096,192] @ concat(fw1,fw2,fw3)[192,64]
__global__ __launch_bounds__(256) void k_fuse(
    const float* __restrict__ Ap, const float* __restrict__ F1,
    const float* __restrict__ F2, const float* __restrict__ F3,
    float* __restrict__ C) {
  __shared__ float As[64][33];
  __shared__ float Bs[32][32];
  const int t = threadIdx.x;
  const int bm = blockIdx.x << 6;
  const int bn = blockIdx.y * 32;
  const int cg = t % 8, rg = t / 8;
  float av[2][4];
#pragma unroll
  for (int i = 0; i < 2; ++i)
#pragma unroll
    for (int j = 0; j < 4; ++j) av[i][j] = 0.f;
  for (int k0 = 0; k0 < 192; k0 += 32) {
    __syncthreads();
#pragma unroll
    for (int i = 0; i < 8; ++i) {
      int idx = t + (i << 8), r = idx >> 5, c = idx & 31;
      As[r][c] = Ap[(size_t)(bm + r) * 192 + k0 + c];
    }
#pragma unroll
    for (int i = 0; i < 4; ++i) {
      int idx = t + (i << 8), r = idx >> 5, c = idx & 31;
      int gr = k0 + r;
      const float* Bp = gr < 64 ? F1 : (gr < 128 ? F2 : F3);
      Bs[r][c] = Bp[(gr & 63) * 64 + bn + c];
    }
    __syncthreads();
#pragma unroll
    for (int k = 0; k < 32; ++k) {
      float b0 = Bs[k][(cg << 2) + 0], b1 = Bs[k][(cg << 2) + 1];
      float b2 = Bs[k][(cg << 2) + 2], b3 = Bs[k][(cg << 2) + 3];
#pragma unroll
      for (int i = 0; i < 2; ++i) {
        float a = As[rg * 2 + i][k];
        av[i][0] = fmaf(a, b0, av[i][0]);
        av[i][1] = fmaf(a, b1, av[i][1]);
        av[i][2] = fmaf(a, b2, av[i][2]);
        av[i][3] = fmaf(a, b3, av[i][3]);
      }
    }
  }
#pragma unroll
  for (int i = 0; i < 2; ++i)
#pragma unroll
    for (int j = 0; j < 4; ++j)
      C[(size_t)(bm + rg * 2 + i) * 64 + bn + (cg << 2) + j] = av[i][j];
}

// transpose+split: in[4096,C] f32 -> hTh/hTl [C][4096] bf16
template<int C>
__global__ void k_tsplit(const float* __restrict__ in, ushort* __restrict__ hTh,
                         ushort* __restrict__ hTl) {
  __shared__ float tl[64][C + 1];
  int t = threadIdx.x;
  int m0 = blockIdx.x * 64;
#pragma unroll
  for (int i = 0; i < (C >> 2); ++i) {
    int idx = t + (i << 8), r = idx / C, c = idx % C;
    tl[r][c] = in[(size_t)(m0 + r) * C + c];
  }
  __syncthreads();
#pragma unroll
  for (int i = 0; i < (C >> 2); ++i) {
    int idx = t + (i << 8), c = idx >> 6, mm = idx & 63;
    float v = tl[mm][c];
    ushort hh = f2bf(v);
    hTh[(size_t)c * N_ + m0 + mm] = hh;
    hTl[(size_t)c * N_ + m0 + mm] = f2bf(v - bf2f(hh));
  }
}

// ---------------------------------------------------------------------------
// consensus aggregation MFMA: part[z][m][n] = sum_k Ab[m,k]*(hTh+hTl)[n,k]
// 128xBN tile, BK=64, split-K chunks of 512, 4 waves, XOR-swizzled LDS.
// ---------------------------------------------------------------------------
template<int BN>
__global__ __launch_bounds__(256) void k_aggm(
    const ushort* __restrict__ Ab, const ushort* __restrict__ hTh,
    const ushort* __restrict__ hTl, float* __restrict__ part) {
  constexpr int NF = BN / 16;
  constexpr int BR = BN / 32;  // B staging passes
  __shared__ __align__(16) ushort lA[8192];
  __shared__ __align__(16) ushort lBh[BN * 64];
  __shared__ __align__(16) ushort lBl[BN * 64];
  const int t = threadIdx.x, lane = t & 63, wave = t >> 6;
  const int bm = blockIdx.x << 7;
  const int kb = blockIdx.y << 9;
  const int hi = lane >> 4, r16 = lane & 15, rx = r16 & 7;
  const int srow = t >> 3, sslot = t & 7;

  f32x4 acc[2][NF];
#pragma unroll
  for (int i = 0; i < 2; ++i)
#pragma unroll
    for (int j = 0; j < NF; ++j)
#pragma unroll
      for (int r = 0; r < 4; ++r) acc[i][j][r] = 0.f;

  short8 sA[4], sBh[BR], sBl[BR];
#define ALOAD(KT)                                                                     \
  {                                                                                   \
    _Pragma("unroll") for (int i = 0; i < 4; ++i) {                                   \
      int row = (i << 5) + srow;                                                      \
      sA[i] = *(const short8*)(Ab + (size_t)(bm + row) * 4096 + kb + (KT) + (sslot << 3)); \
    }                                                                                 \
    _Pragma("unroll") for (int i = 0; i < BR; ++i) {                                  \
      int row = (i << 5) + srow;                                                      \
      sBh[i] = *(const short8*)(hTh + (size_t)row * 4096 + kb + (KT) + (sslot << 3)); \
      sBl[i] = *(const short8*)(hTl + (size_t)row * 4096 + kb + (KT) + (sslot << 3)); \
    }                                                                                 \
  }
  ALOAD(0);
  for (int kt = 0; kt < 512; kt += 64) {
    __syncthreads();
#pragma unroll
    for (int i = 0; i < 4; ++i) {
      int row = (i << 5) + srow;
      *(short8*)(&lA[row * 64 + ((sslot ^ (row & 7)) << 3)]) = sA[i];
    }
#pragma unroll
    for (int i = 0; i < BR; ++i) {
      int row = (i << 5) + srow;
      *(short8*)(&lBh[row * 64 + ((sslot ^ (row & 7)) << 3)]) = sBh[i];
      *(short8*)(&lBl[row * 64 + ((sslot ^ (row & 7)) << 3)]) = sBl[i];
    }
    __syncthreads();
    if (kt + 64 < 512) ALOAD(kt + 64);
#pragma unroll
    for (int k0 = 0; k0 < 2; ++k0) {
      const int soff = (((k0 << 2) + hi) ^ rx) << 3;
      short8 af[2], bh[NF], bl[NF];
#pragma unroll
      for (int mi = 0; mi < 2; ++mi) {
        int row = wave * 32 + mi * 16 + r16;
        af[mi] = *(const short8*)(&lA[row * 64 + soff]);
      }
#pragma unroll
      for (int ni = 0; ni < NF; ++ni) {
        int row = ni * 16 + r16;
        bh[ni] = *(const short8*)(&lBh[row * 64 + soff]);
        bl[ni] = *(const short8*)(&lBl[row * 64 + soff]);
      }
#pragma unroll
      for (int mi = 0; mi < 2; ++mi)
#pragma unroll
        for (int ni = 0; ni < NF; ++ni) {
          acc[mi][ni] = __builtin_amdgcn_mfma_f32_16x16x32_bf16(af[mi], bh[ni], acc[mi][ni], 0, 0, 0);
          acc[mi][ni] = __builtin_amdgcn_mfma_f32_16x16x32_bf16(af[mi], bl[ni], acc[mi][ni], 0, 0, 0);
        }
    }
  }
#pragma unroll
  for (int mi = 0; mi < 2; ++mi)
#pragma unroll
    for (int ni = 0; ni < NF; ++ni)
#pragma unroll
      for (int r2 = 0; r2 < 4; ++r2) {
        int gm = bm + wave * 32 + mi * 16 + (hi << 2) + r2;
        int gn = ni * 16 + r16;
        part[((size_t)blockIdx.y * 4096 + gm) * BN + gn] = acc[mi][ni][r2];
      }
#undef ALOAD
}

// sum split-K partials, apply norm+bias(+relu), optional featT write
template<int C, int RELU, int WFT>
__global__ void k_fincons(const float* __restrict__ part, const float* __restrict__ rs,
                          const float* __restrict__ bias, float* __restrict__ out,
                          float* __restrict__ featT) {
  int i = blockIdx.x * 256 + threadIdx.x;
  int m = i / C, c = i % C;
  float s = 0.f;
#pragma unroll
  for (int z = 0; z < 8; ++z) s += part[((size_t)z * 4096 + m) * C + c];
  float v = s * rs[m] + bias[c];
  if (RELU) v = fmaxf(v, 0.f);
  out[i] = v;
  if (WFT) featT[(size_t)c * N_ + m] = v;
}

// ---------------------------------------------------------------------------
// bf16-split MFMA GEMM (GFN), 128x128 tile, BK=64, 4 waves, XOR-swizzled LDS,
// issue-early register double-buffer.
// ---------------------------------------------------------------------------
template<int NA, int NB, int EPI>
__global__ __launch_bounds__(256, 2) void k_mfma(
    const ushort* __restrict__ A0, const ushort* __restrict__ A1,
    const ushort* __restrict__ B0, const ushort* __restrict__ B1,
    const float* __restrict__ bias, float* __restrict__ Cf,
    ushort* __restrict__ Oh, ushort* __restrict__ Ol, int Nn, int K) {
  constexpr int NOPS = NA + NB;
  __shared__ __align__(16) ushort lds[NOPS * 8192];
  const int t = threadIdx.x, lane = t & 63;
  const int wave = t >> 6, wm = wave >> 1, wn = wave & 1;
  const int bm = blockIdx.y << 7, bn = blockIdx.x << 7;
  const int hi = lane >> 4, r16 = lane & 15, rx = r16 & 7;
  const int srow = t >> 3, sslot = t & 7;

  const ushort* gsrc[4];
  int rb[4];
  {
    int no = 0;
    gsrc[no] = A0; rb[no] = bm; no++;
    if (NA > 1) { gsrc[no] = A1; rb[no] = bm; no++; }
    gsrc[no] = B0; rb[no] = bn; no++;
    if (NB > 1) { gsrc[no] = B1; rb[no] = bn; no++; }
  }

  f32x4 acc[4][4];
#pragma unroll
  for (int i = 0; i < 4; ++i)
#pragma unroll
    for (int j = 0; j < 4; ++j)
#pragma unroll
      for (int r = 0; r < 4; ++r) acc[i][j][r] = 0.f;

  short8 stg[NOPS][4];
#define LOADT(KT)                                                                      \
  {                                                                                    \
    _Pragma("unroll") for (int op = 0; op < NOPS; ++op)                                \
        _Pragma("unroll") for (int i = 0; i < 4; ++i) {                                \
      int row = (i << 5) + srow;                                                       \
      stg[op][i] = *(const short8*)(gsrc[op] + (size_t)(rb[op] + row) * K + (KT) +     \
                                    (sslot << 3));                                     \
    }                                                                                  \
  }

  LOADT(0);
  for (int kt = 0; kt < K; kt += 64) {
    __syncthreads();
#pragma unroll
    for (int op = 0; op < NOPS; ++op)
#pragma unroll
      for (int i = 0; i < 4; ++i) {
        int row = (i << 5) + srow;
        *(short8*)(&lds[op * 8192 + row * 64 + ((sslot ^ (row & 7)) << 3)]) = stg[op][i];
      }
    __syncthreads();
    if (kt + 64 < K) LOADT(kt + 64);
#pragma unroll
    for (int k0 = 0; k0 < 2; ++k0) {
      const int soff = (((k0 << 2) + hi) ^ rx) << 3;
      short8 af[NA][4], bf[NB][4];
#pragma unroll
      for (int mi = 0; mi < 4; ++mi) {
        int row = (wm << 6) + (mi << 4) + r16;
        af[0][mi] = *(const short8*)(&lds[row * 64 + soff]);
        if (NA > 1) af[1][mi] = *(const short8*)(&lds[8192 + row * 64 + soff]);
      }
#pragma unroll
      for (int ni = 0; ni < 4; ++ni) {
        int row = (wn << 6) + (ni << 4) + r16;
        bf[0][ni] = *(const short8*)(&lds[NA * 8192 + row * 64 + soff]);
        if (NB > 1) bf[1][ni] = *(const short8*)(&lds[(NA + 1) * 8192 + row * 64 + soff]);
      }
#pragma unroll
      for (int mi = 0; mi < 4; ++mi)
#pragma unroll
        for (int ni = 0; ni < 4; ++ni) {
          acc[mi][ni] = __builtin_amdgcn_mfma_f32_16x16x32_bf16(af[0][mi], bf[0][ni], acc[mi][ni], 0, 0, 0);
          if (NB > 1)
            acc[mi][ni] = __builtin_amdgcn_mfma_f32_16x16x32_bf16(af[0][mi], bf[1][ni], acc[mi][ni], 0, 0, 0);
          if (NA > 1)
            acc[mi][ni] = __builtin_amdgcn_mfma_f32_16x16x32_bf16(af[1][mi], bf[0][ni], acc[mi][ni], 0, 0, 0);
        }
    }
  }
#pragma unroll
  for (int mi = 0; mi < 4; ++mi)
#pragma unroll
    for (int ni = 0; ni < 4; ++ni) {
      const int gn = bn + (wn << 6) + (ni << 4) + r16;
      const float bv = bias[gn];
#pragma unroll
      for (int r2 = 0; r2 < 4; ++r2) {
        const int gm = bm + (wm << 6) + (mi << 4) + (hi << 2) + r2;
        float v = acc[mi][ni][r2] + bv;
        if (EPI == 1) {
          v = fmaxf(v, 0.f);
          ushort hh = f2bf(v);
          Oh[(size_t)gm * Nn + gn] = hh;
          Ol[(size_t)gm * Nn + gn] = f2bf(v - bf2f(hh));
        } else {
          Cf[(size_t)gm * Nn + gn] = v;
        }
      }
    }
#undef LOADT
}

// ---------------------------------------------------------------------------
extern "C" void kernel_launch(void* const* d_in, const int* in_sizes, int n_in,
                              void* d_out, int out_size, void* d_ws, size_t ws_size,
                              hipStream_t stream) {
  const float* data[3] = {(const float*)d_in[0], (const float*)d_in[1], (const float*)d_in[2]};
  const int D[3] = {512, 256, 128};
  const int* src[3] = {(const int*)d_in[3], (const int*)d_in[6], (const int*)d_in[9]};
  const int* dst[3] = {(const int*)d_in[4], (const int*)d_in[7], (const int*)d_in[10]};
  const float* w0[3] = {(const float*)d_in[12], (const float*)d_in[16], (const float*)d_in[20]};
  const float* b0[3] = {(const float*)d_in[13], (const float*)d_in[17], (const float*)d_in[21]};
  const float* w1[3] = {(const float*)d_in[14], (const float*)d_in[18], (const float*)d_in[22]};
  const float* b1[3] = {(const float*)d_in[15], (const float*)d_in[19], (const float*)d_in[23]};
  const float* wm0 = (const float*)d_in[24];
  const float* bm0 = (const float*)d_in[25];
  const float* wm1 = (const float*)d_in[26];
  const float* bm1 = (const float*)d_in[27];
  const float* fw[3] = {(const float*)d_in[28], (const float*)d_in[29], (const float*)d_in[30]};
  const float* gw1 = (const float*)d_in[31];
  const float* gb1 = (const float*)d_in[32];
  const float* gw2 = (const float*)d_in[33];
  const float* gb2 = (const float*)d_in[34];

  float* outf = (float*)d_out;
  float* adj_r = outf;                  // output 0
  float* adj_rec = outf + 16777216;     // output 1
  float* feat = outf + 33554432;        // output 2
  // adj_r region overlay (dead before G2 writes adj_r):
  ushort* w1h = (ushort*)outf;          // [2048,4096]
  ushort* w1l = w1h + 8388608;
  ushort* adjin = w1h + 16777216;       // [4096,4096]
  // adj_rec region overlay (dead before final feat@featT):
  ushort* o1u = (ushort*)adj_rec;
  ushort* h1h = o1u;                    // [4096,2048]
  ushort* h1l = o1u + 8388608;
  ushort* w2h = o1u + 16777216;         // [4096,2048]
  ushort* w2l = o1u + 25165824;
  ushort* Ab = o1u;                     // A bf16, after G2 (h1 dead)

  float* wsf = (float*)d_ws;
  float* degA = wsf + 24576;
  unsigned* bmp = (unsigned*)(wsf + 28672);  // phase a only
  // phase b
  float* hX = wsf + 28672;        // [4096,128]
  float* hbuf = wsf + 552960;     // [4096,128]
  float* t2 = wsf + 1077248;      // [4096,64]
  float* fvI = wsf + 1339392;     // [4096,192] interleaved
  int* csr = (int*)(wsf + 2125824);
  float* zpre = wsf + 28672;      // after views done
  float* zb = wsf + 290816;
  // phase c
  float* part0 = wsf + 552960;    // [8][4096][64]  (ends 2650112)
  float* t0 = wsf + 28672;        // [4096,64]
  ushort* hT0h = (ushort*)(wsf + 290816);  // [64][4096]
  ushort* hT0l = hT0h + 262144;
  float* h1c = wsf + 28672;       // [4096,64]
  float* t1 = wsf + 290816;       // [4096,32]
  ushort* hT1h = (ushort*)(wsf + 421888);  // [32][4096]
  ushort* hT1l = hT1h + 131072;
  float* part1 = wsf + 552960;    // [8][4096][32]
  float* featT = wsf + 28672;     // [32,4096]

  // ---- phase (a): GFN ----
  hipMemsetAsync(wsf, 0, (size_t)1601536 * 4, stream);  // degs + degA + bitmaps
  k_edges<<<768, 256, 0, stream>>>(src[0], dst[0], src[1], dst[1], src[2], dst[2], wsf, bmp);
  k_prep<<<24576, 256, 0, stream>>>(bmp, adjin, (const float4*)gw1, (const float4*)gw2,
                                    w1h, w1l, w2h, w2l);
  k_mfma<1, 2, 1><<<dim3(16, 32), 256, 0, stream>>>(
      adjin, nullptr, w1h, w1l, gb1, nullptr, h1h, h1l, 2048, 4096);
  k_mfma<2, 2, 2><<<dim3(32, 32), 256, 0, stream>>>(
      h1h, h1l, w2h, w2l, gb2, adj_r, nullptr, nullptr, 4096, 2048);
  k_buildA<<<dim3(64, 64), 256, 0, stream>>>(adj_r, Ab, degA);

  // ---- phase (b): CSR + per-view stacks + fusion ----
  k_scan7<<<7, 256, 0, stream>>>(wsf, csr);
  k_fill<<<768, 256, 0, stream>>>(src[0], dst[0], src[1], dst[1], src[2], dst[2], csr);
  for (int v = 0; v < 3; ++v) {
    const float* rso = wsf + v * 8192;
    const float* rsi = wsf + v * 8192 + 4096;
    const int* csrv = csr + v * CSR_STRIDE;
    k_gemm<32, 2, 1><<<dim3(64, 4), 256, 0, stream>>>(
        data[v], D[v], w0[v], 128, hX, 128, D[v], rso);
    k_agg<128, 1><<<2048, 256, 0, stream>>>(hX, csrv, rsi, b0[v], hbuf, 128, 0);
    k_gemm<32, 2, 1><<<dim3(64, 2), 256, 0, stream>>>(
        hbuf, 128, w1[v], 64, t2, 64, 128, rso);
    k_agg<64, 0><<<1024, 256, 0, stream>>>(t2, csrv, rsi, b1[v], fvI, 192, v * 64);
  }
  k_fuse<<<dim3(64, 2), 256, 0, stream>>>(fvI, fw[0], fw[1], fw[2], zpre);
  k_softmax<<<1024, 256, 0, stream>>>(zpre, zb);

  // ---- phase (c): consensus GraphConvs (MFMA) + adj_rec ----
  k_gemm<32, 2, 1><<<dim3(64, 2), 256, 0, stream>>>(zb, 64, wm0, 64, t0, 64, 64, degA);
  k_tsplit<64><<<64, 256, 0, stream>>>(t0, hT0h, hT0l);
  k_aggm<64><<<dim3(32, 8), 256, 0, stream>>>(Ab, hT0h, hT0l, part0);
  k_fincons<64, 1, 0><<<1024, 256, 0, stream>>>(part0, degA, bm0, h1c, nullptr);
  k_gemm<32, 2, 1><<<dim3(64, 1), 256, 0, stream>>>(h1c, 64, wm1, 32, t1, 32, 64, degA);
  k_tsplit<32><<<64, 256, 0, stream>>>(t1, hT1h, hT1l);
  k_aggm<32><<<dim3(32, 8), 256, 0, stream>>>(Ab, hT1h, hT1l, part1);
  k_fincons<32, 0, 1><<<512, 256, 0, stream>>>(part1, degA, bm1, feat, featT);
  k_gemm<128, 8, 0><<<dim3(64, 32), 256, 0, stream>>>(
      feat, 32, featT, 4096, adj_rec, 4096, 32, nullptr);
}

// Round 4
// 894.060 us; speedup vs baseline: 1.3840x; 1.0649x over previous
//
#include <hip/hip_runtime.h>

// GAE pipeline for MI355X. N=4096 nodes, E=65536 edges/view.
// Phase a: edges->bitmaps->adjin, weight prep, G1/G2 (bf16-split MFMA, G2 also
//          emits the p-threshold bitmap), buildA2 from bitmap.
// Phase b: CSR build, per-view stacks via split-MFMA GEMMs + gather-agg, fusion.
// Phase c: consensus GraphConvs via MFMA A@h (split-K partials), MFMA adj_rec.

#define N_ 4096
#define E_ 65536
#define CSR_STRIDE 73732  // ints per view: ptr 4100, cur 4096, cidx 65536

typedef __attribute__((ext_vector_type(8))) short short8;
typedef __attribute__((ext_vector_type(4))) float f32x4;

__device__ __forceinline__ float bf2f(unsigned short u) {
  union { unsigned int i; float f; } v; v.i = ((unsigned int)u) << 16; return v.f;
}
__device__ __forceinline__ unsigned short f2bf(float f) {
  union { float f; unsigned int i; } v; v.f = f;
  return (unsigned short)((v.i + 0x7fffu + ((v.i >> 16) & 1u)) >> 16);
}

// ---------------------------------------------------------------------------
// edge pass: degree counts + per-view dedupe bitmaps
// ---------------------------------------------------------------------------
__global__ void k_edges(const int* __restrict__ s1, const int* __restrict__ d1,
                        const int* __restrict__ s2, const int* __restrict__ d2,
                        const int* __restrict__ s3, const int* __restrict__ d3,
                        float* __restrict__ wd, unsigned* __restrict__ bmp) {
  int v = blockIdx.x >> 8;
  int e = (blockIdx.x & 255) * 256 + threadIdx.x;
  const int* sv = v == 0 ? s1 : (v == 1 ? s2 : s3);
  const int* dv = v == 0 ? d1 : (v == 1 ? d2 : d3);
  int s = sv[e], d = dv[e];
  atomicAdd(&wd[v * 8192 + s], 1.f);
  atomicAdd(&wd[v * 8192 + 4096 + d], 1.f);
  unsigned idx = (unsigned)s * 4096u + (unsigned)d;
  atomicOr(&bmp[v * 524288 + (idx >> 5)], 1u << (idx & 31));
}

// bitmaps -> adjin bf16, and split gw1/gw2 into bf16 hi/lo (one launch)
__global__ void k_prep(const unsigned* __restrict__ bmp, ushort* __restrict__ adjin,
                       const float4* __restrict__ g1, const float4* __restrict__ g2,
                       ushort* __restrict__ w1h, ushort* __restrict__ w1l,
                       ushort* __restrict__ w2h, ushort* __restrict__ w2l) {
  int i = blockIdx.x * 256 + threadIdx.x;
  if (i < 2097152) {
    int w = i >> 2, sh = (i & 3) << 3;
    unsigned a = bmp[w] >> sh, b = bmp[524288 + w] >> sh, c = bmp[1048576 + w] >> sh;
    short8 o;
#pragma unroll
    for (int k = 0; k < 8; ++k) {
      int cnt = ((a >> k) & 1) + ((b >> k) & 1) + ((c >> k) & 1);
      o[k] = (short)f2bf((float)cnt);
    }
    *(short8*)(adjin + (size_t)i * 8) = o;
  } else {
    int i2 = i - 2097152;
    int hf = i2 >= 2097152;
    int j = i2 & 2097151;
    float4 x = hf ? g2[j] : g1[j];
    ushort* ph = hf ? w2h : w1h;
    ushort* pl = hf ? w2l : w1l;
    ushort4 h, l;
    h.x = f2bf(x.x); l.x = f2bf(x.x - bf2f(h.x));
    h.y = f2bf(x.y); l.y = f2bf(x.y - bf2f(h.y));
    h.z = f2bf(x.z); l.z = f2bf(x.z - bf2f(h.z));
    h.w = f2bf(x.w); l.w = f2bf(x.w - bf2f(h.w));
    *(ushort4*)(ph + (size_t)j * 4) = h;
    *(ushort4*)(pl + (size_t)j * 4) = l;
  }
}

// transpose+split small weights: W[Kw,Nw] f32 -> dh/dl [Nw][os] bf16 (col k)
struct WSeg { const float* src; ushort* dh; ushort* dl; int Kw; int Nw; int sh; int os; int oo; };
struct WArgs { WSeg s[11]; };

__global__ void k_wprep(WArgs wa) {
  WSeg sg = wa.s[blockIdx.y];
  int total = sg.Kw << sg.sh;
  for (int i = blockIdx.x * 256 + threadIdx.x; i < total; i += 8192) {
    int k = i >> sg.sh, n = i & (sg.Nw - 1);
    float v = sg.src[i];
    ushort hh = f2bf(v);
    sg.dh[(size_t)n * sg.os + sg.oo + k] = hh;
    sg.dl[(size_t)n * sg.os + sg.oo + k] = f2bf(v - bf2f(hh));
  }
}

// blocks 0-2: CSR scan per view (+ rsqrt degi); blocks 3-6: rsqrt dego/degA
__global__ void k_scan7(float* __restrict__ wd, int* __restrict__ csr) {
  int b = blockIdx.x, t = threadIdx.x;
  if (b < 3) {
    float* di = wd + b * 8192 + 4096;
    int* ptr = csr + b * CSR_STRIDE;
    int* cur = ptr + 4100;
    __shared__ int part[256];
    int local[16];
    float cnt[16];
    int s = 0;
#pragma unroll
    for (int i = 0; i < 16; ++i) { cnt[i] = di[t * 16 + i]; local[i] = s; s += (int)cnt[i]; }
    part[t] = s;
    __syncthreads();
    for (int o = 1; o < 256; o <<= 1) {
      int x = (t >= o) ? part[t - o] : 0;
      __syncthreads();
      part[t] += x;
      __syncthreads();
    }
    int base = (t > 0) ? part[t - 1] : 0;
#pragma unroll
    for (int i = 0; i < 16; ++i) {
      ptr[t * 16 + i] = base + local[i];
      cur[t * 16 + i] = 0;
      di[t * 16 + i] = 1.f / sqrtf(fmaxf(cnt[i], 1.f));
    }
    if (t == 255) ptr[4096] = part[255];
  } else {
    int off = (b == 3) ? 0 : (b == 4) ? 8192 : (b == 5) ? 16384 : 24576;
#pragma unroll
    for (int i = 0; i < 16; ++i) {
      int idx = off + t * 16 + i;
      wd[idx] = 1.f / sqrtf(fmaxf(wd[idx], 1.f));
    }
  }
}

__global__ void k_fill(const int* __restrict__ s1, const int* __restrict__ d1,
                       const int* __restrict__ s2, const int* __restrict__ d2,
                       const int* __restrict__ s3, const int* __restrict__ d3,
                       int* __restrict__ csr) {
  int v = blockIdx.x >> 8;
  int e = (blockIdx.x & 255) * 256 + threadIdx.x;
  const int* sv = v == 0 ? s1 : (v == 1 ? s2 : s3);
  const int* dv = v == 0 ? d1 : (v == 1 ? d2 : d3);
  int* ptr = csr + v * CSR_STRIDE;
  int* cur = ptr + 4100;
  int* cidx = cur + 4096;
  int d = dv[e];
  int pos = ptr[d] + atomicAdd(&cur[d], 1);
  cidx[pos] = sv[e];
}

// gather-aggregate across 3 views (grid.y=view); strided col-strips
struct AB { const float* b[3]; };
template<int C, int RELU>
__global__ void k_agg3(const float* __restrict__ hbase, int is,
                       const int* __restrict__ csr, const float* __restrict__ wd,
                       AB ab, float* __restrict__ out, int os) {
  int v = blockIdx.y;
  const int* ptr = csr + v * CSR_STRIDE;
  const int* cidx = ptr + 4100 + 4096;
  const float* rs = wd + v * 8192 + 4096;
  const float* bias = ab.b[v];
  const float* hv = hbase + v * C;
  float* ov = out + v * C;
  int wave = threadIdx.x >> 6, lane = threadIdx.x & 63;
  int dst = (blockIdx.x << 2) + wave;
  int e0 = ptr[dst], e1 = ptr[dst + 1];
  float sc = rs[dst];
  if (C == 128) {
    float2 acc = {0.f, 0.f};
    for (int e = e0; e < e1; ++e) {
      float2 x = *(const float2*)(hv + (size_t)cidx[e] * is + lane * 2);
      acc.x += x.x; acc.y += x.y;
    }
    float2 r;
    r.x = acc.x * sc + bias[lane * 2];
    r.y = acc.y * sc + bias[lane * 2 + 1];
    if (RELU) { r.x = fmaxf(r.x, 0.f); r.y = fmaxf(r.y, 0.f); }
    *(float2*)(ov + (size_t)dst * os + lane * 2) = r;
  } else {
    float acc = 0.f;
    for (int e = e0; e < e1; ++e) acc += hv[(size_t)cidx[e] * is + lane];
    float r = acc * sc + bias[lane];
    if (RELU) r = fmaxf(r, 0.f);
    ov[(size_t)dst * os + lane] = r;
  }
}

__global__ void k_softmax(const float* __restrict__ zp, float* __restrict__ z) {
  int row = blockIdx.x * 4 + (threadIdx.x >> 6);
  int lane = threadIdx.x & 63;
  float v = zp[row * 64 + lane];
  float m = v;
  for (int o = 32; o; o >>= 1) m = fmaxf(m, __shfl_xor(m, o, 64));
  float e = expf(v - m);
  float s = e;
  for (int o = 32; o; o >>= 1) s += __shfl_xor(s, o, 64);
  z[row * 64 + lane] = e / s;
}

// A = ((p + p^T) != 0) + I from the p-bitmap (pb: ushort[4096][256])
__global__ void k_buildA2(const ushort* __restrict__ pb, ushort* __restrict__ Ab,
                          float* __restrict__ degA) {
  int bi = blockIdx.y, bj = blockIdx.x;
  int t = threadIdx.x, w = t >> 6, lane = t & 63;
  int gj = bj * 64 + lane;
  unsigned long long tp = *(const unsigned long long*)(pb + (size_t)gj * 256 + bi * 4);
  for (int rr = 0; rr < 16; ++rr) {
    int r = w * 16 + rr;
    int gi = bi * 64 + r;
    unsigned long long prow = *(const unsigned long long*)(pb + (size_t)gi * 256 + bj * 4);
    int pbit = (int)((prow >> lane) & 1ull);
    int tbit = (int)((tp >> r) & 1ull);
    float a = ((pbit | tbit) ? 1.f : 0.f) + (gi == gj ? 1.f : 0.f);
    Ab[(size_t)gi * N_ + gj] = f2bf(a);
    float s = a;
    for (int o = 32; o; o >>= 1) s += __shfl_xor(s, o, 64);
    if (lane == 0) atomicAdd(&degA[gi], s);
  }
}

// ---------------------------------------------------------------------------
// generic split-MFMA GEMM: C[M,N] = rs .* (A[M,K] @ B), B pre-transposed+split
// as BT hi/lo [N][K] bf16. A f32 converted to hi/lo at staging. 3 MFMA terms.
// 128-row tile, BK=64, 4 waves (32 rows each), XOR-swizzled LDS.
// ---------------------------------------------------------------------------
struct GSeg { const float* A; const ushort* bh; const ushort* bl; float* C;
              const float* rs; int lda; int ldc; int K; };
struct GArgs { GSeg s[3]; };

template<int BN, int NSEG>
__global__ __launch_bounds__(256) void k_gemms(GArgs ga) {
  constexpr int NF = BN / 16;
  constexpr int BR = BN / 32;
  __shared__ __align__(16) ushort lAh[8192], lAl[8192];
  __shared__ __align__(16) ushort lBh[BN * 64], lBl[BN * 64];
  const GSeg sg = ga.s[NSEG == 1 ? 0 : blockIdx.y];
  const int t = threadIdx.x, lane = t & 63, wave = t >> 6;
  const int bm = blockIdx.x << 7;
  const int hi = lane >> 4, r16 = lane & 15, rx = r16 & 7;
  const int srow = t >> 3, sslot = t & 7;

  f32x4 acc[2][NF];
#pragma unroll
  for (int i = 0; i < 2; ++i)
#pragma unroll
    for (int j = 0; j < NF; ++j)
#pragma unroll
      for (int r = 0; r < 4; ++r) acc[i][j][r] = 0.f;

  float4 sa[4][2];
  short8 sbh[BR], sbl[BR];
#define GLOAD(KT)                                                                     \
  {                                                                                   \
    _Pragma("unroll") for (int i = 0; i < 4; ++i) {                                   \
      int row = (i << 5) + srow;                                                      \
      const float* ap = sg.A + (size_t)(bm + row) * sg.lda + (KT) + (sslot << 3);     \
      sa[i][0] = *(const float4*)ap;                                                  \
      sa[i][1] = *(const float4*)(ap + 4);                                            \
    }                                                                                 \
    _Pragma("unroll") for (int i = 0; i < BR; ++i) {                                  \
      int row = (i << 5) + srow;                                                      \
      sbh[i] = *(const short8*)(sg.bh + (size_t)row * sg.K + (KT) + (sslot << 3));    \
      sbl[i] = *(const short8*)(sg.bl + (size_t)row * sg.K + (KT) + (sslot << 3));    \
    }                                                                                 \
  }
  GLOAD(0);
  for (int kt = 0; kt < sg.K; kt += 64) {
    __syncthreads();
#pragma unroll
    for (int i = 0; i < 4; ++i) {
      int row = (i << 5) + srow;
      short8 h8, l8;
      const float* fp = (const float*)&sa[i][0];
#pragma unroll
      for (int j = 0; j < 8; ++j) {
        float f = fp[j];
        ushort hh = f2bf(f);
        h8[j] = (short)hh;
        l8[j] = (short)f2bf(f - bf2f(hh));
      }
      int so = row * 64 + ((sslot ^ (row & 7)) << 3);
      *(short8*)(&lAh[so]) = h8;
      *(short8*)(&lAl[so]) = l8;
    }
#pragma unroll
    for (int i = 0; i < BR; ++i) {
      int row = (i << 5) + srow;
      int so = row * 64 + ((sslot ^ (row & 7)) << 3);
      *(short8*)(&lBh[so]) = sbh[i];
      *(short8*)(&lBl[so]) = sbl[i];
    }
    __syncthreads();
    if (kt + 64 < sg.K) GLOAD(kt + 64);
#pragma unroll
    for (int k0 = 0; k0 < 2; ++k0) {
      const int soff = (((k0 << 2) + hi) ^ rx) << 3;
      short8 ah_[2], al_[2];
#pragma unroll
      for (int mi = 0; mi < 2; ++mi) {
        int row = wave * 32 + mi * 16 + r16;
        ah_[mi] = *(const short8*)(&lAh[row * 64 + soff]);
        al_[mi] = *(const short8*)(&lAl[row * 64 + soff]);
      }
#pragma unroll
      for (int nf = 0; nf < NF; ++nf) {
        int row = nf * 16 + r16;
        short8 bh_ = *(const short8*)(&lBh[row * 64 + soff]);
        short8 bl_ = *(const short8*)(&lBl[row * 64 + soff]);
#pragma unroll
        for (int mi = 0; mi < 2; ++mi) {
          acc[mi][nf] = __builtin_amdgcn_mfma_f32_16x16x32_bf16(ah_[mi], bh_, acc[mi][nf], 0, 0, 0);
          acc[mi][nf] = __builtin_amdgcn_mfma_f32_16x16x32_bf16(ah_[mi], bl_, acc[mi][nf], 0, 0, 0);
          acc[mi][nf] = __builtin_amdgcn_mfma_f32_16x16x32_bf16(al_[mi], bh_, acc[mi][nf], 0, 0, 0);
        }
      }
    }
  }
#pragma unroll
  for (int mi = 0; mi < 2; ++mi)
#pragma unroll
    for (int nf = 0; nf < NF; ++nf)
#pragma unroll
      for (int r2 = 0; r2 < 4; ++r2) {
        int gm = bm + wave * 32 + mi * 16 + (hi << 2) + r2;
        int gn = nf * 16 + r16;
        float v = acc[mi][nf][r2];
        if (sg.rs) v *= sg.rs[gm];
        sg.C[(size_t)gm * sg.ldc + gn] = v;
      }
#undef GLOAD
}

// transpose+split: in[4096,C] f32 -> hTh/hTl [C][4096] bf16
template<int C>
__global__ void k_tsplit(const float* __restrict__ in, ushort* __restrict__ hTh,
                         ushort* __restrict__ hTl) {
  __shared__ float tl[64][C + 1];
  int t = threadIdx.x;
  int m0 = blockIdx.x * 64;
#pragma unroll
  for (int i = 0; i < (C >> 2); ++i) {
    int idx = t + (i << 8), r = idx / C, c = idx % C;
    tl[r][c] = in[(size_t)(m0 + r) * C + c];
  }
  __syncthreads();
#pragma unroll
  for (int i = 0; i < (C >> 2); ++i) {
    int idx = t + (i << 8), c = idx >> 6, mm = idx & 63;
    float v = tl[mm][c];
    ushort hh = f2bf(v);
    hTh[(size_t)c * N_ + m0 + mm] = hh;
    hTl[(size_t)c * N_ + m0 + mm] = f2bf(v - bf2f(hh));
  }
}

// ---------------------------------------------------------------------------
// consensus aggregation MFMA: part[z][m][n] = sum_k Ab[m,k]*(hTh+hTl)[n,k]
// ---------------------------------------------------------------------------
template<int BN>
__global__ __launch_bounds__(256) void k_aggm(
    const ushort* __restrict__ Ab, const ushort* __restrict__ hTh,
    const ushort* __restrict__ hTl, float* __restrict__ part) {
  constexpr int NF = BN / 16;
  constexpr int BR = BN / 32;
  __shared__ __align__(16) ushort lA[8192];
  __shared__ __align__(16) ushort lBh[BN * 64];
  __shared__ __align__(16) ushort lBl[BN * 64];
  const int t = threadIdx.x, lane = t & 63, wave = t >> 6;
  const int bm = blockIdx.x << 7;
  const int kb = blockIdx.y << 9;
  const int hi = lane >> 4, r16 = lane & 15, rx = r16 & 7;
  const int srow = t >> 3, sslot = t & 7;

  f32x4 acc[2][NF];
#pragma unroll
  for (int i = 0; i < 2; ++i)
#pragma unroll
    for (int j = 0; j < NF; ++j)
#pragma unroll
      for (int r = 0; r < 4; ++r) acc[i][j][r] = 0.f;

  short8 sA[4], sBh[BR], sBl[BR];
#define ALOAD(KT)                                                                     \
  {                                                                                   \
    _Pragma("unroll") for (int i = 0; i < 4; ++i) {                                   \
      int row = (i << 5) + srow;                                                      \
      sA[i] = *(const short8*)(Ab + (size_t)(bm + row) * 4096 + kb + (KT) + (sslot << 3)); \
    }                                                                                 \
    _Pragma("unroll") for (int i = 0; i < BR; ++i) {                                  \
      int row = (i << 5) + srow;                                                      \
      sBh[i] = *(const short8*)(hTh + (size_t)row * 4096 + kb + (KT) + (sslot << 3)); \
      sBl[i] = *(const short8*)(hTl + (size_t)row * 4096 + kb + (KT) + (sslot << 3)); \
    }                                                                                 \
  }
  ALOAD(0);
  for (int kt = 0; kt < 512; kt += 64) {
    __syncthreads();
#pragma unroll
    for (int i = 0; i < 4; ++i) {
      int row = (i << 5) + srow;
      *(short8*)(&lA[row * 64 + ((sslot ^ (row & 7)) << 3)]) = sA[i];
    }
#pragma unroll
    for (int i = 0; i < BR; ++i) {
      int row = (i << 5) + srow;
      *(short8*)(&lBh[row * 64 + ((sslot ^ (row & 7)) << 3)]) = sBh[i];
      *(short8*)(&lBl[row * 64 + ((sslot ^ (row & 7)) << 3)]) = sBl[i];
    }
    __syncthreads();
    if (kt + 64 < 512) ALOAD(kt + 64);
#pragma unroll
    for (int k0 = 0; k0 < 2; ++k0) {
      const int soff = (((k0 << 2) + hi) ^ rx) << 3;
      short8 af[2], bh[NF], bl[NF];
#pragma unroll
      for (int mi = 0; mi < 2; ++mi) {
        int row = wave * 32 + mi * 16 + r16;
        af[mi] = *(const short8*)(&lA[row * 64 + soff]);
      }
#pragma unroll
      for (int ni = 0; ni < NF; ++ni) {
        int row = ni * 16 + r16;
        bh[ni] = *(const short8*)(&lBh[row * 64 + soff]);
        bl[ni] = *(const short8*)(&lBl[row * 64 + soff]);
      }
#pragma unroll
      for (int mi = 0; mi < 2; ++mi)
#pragma unroll
        for (int ni = 0; ni < NF; ++ni) {
          acc[mi][ni] = __builtin_amdgcn_mfma_f32_16x16x32_bf16(af[mi], bh[ni], acc[mi][ni], 0, 0, 0);
          acc[mi][ni] = __builtin_amdgcn_mfma_f32_16x16x32_bf16(af[mi], bl[ni], acc[mi][ni], 0, 0, 0);
        }
    }
  }
#pragma unroll
  for (int mi = 0; mi < 2; ++mi)
#pragma unroll
    for (int ni = 0; ni < NF; ++ni)
#pragma unroll
      for (int r2 = 0; r2 < 4; ++r2) {
        int gm = bm + wave * 32 + mi * 16 + (hi << 2) + r2;
        int gn = ni * 16 + r16;
        part[((size_t)blockIdx.y * 4096 + gm) * BN + gn] = acc[mi][ni][r2];
      }
#undef ALOAD
}

// sum split-K partials, apply norm+bias(+relu); WFT: also write feat bf16 hi/lo
template<int C, int RELU, int WFT>
__global__ void k_fincons(const float* __restrict__ part, const float* __restrict__ rs,
                          const float* __restrict__ bias, float* __restrict__ out,
                          ushort* __restrict__ fh, ushort* __restrict__ fl) {
  int i = blockIdx.x * 256 + threadIdx.x;
  int m = i / C, c = i % C;
  float s = 0.f;
#pragma unroll
  for (int z = 0; z < 8; ++z) s += part[((size_t)z * 4096 + m) * C + c];
  float v = s * rs[m] + bias[c];
  if (RELU) v = fmaxf(v, 0.f);
  out[i] = v;
  if (WFT) {
    ushort hh = f2bf(v);
    fh[i] = hh;
    fl[i] = f2bf(v - bf2f(hh));
  }
}

// adj_rec = F @ F^T via direct-fragment MFMA (K=32, no LDS)
__global__ __launch_bounds__(256) void k_rec(const ushort* __restrict__ fh,
                                             const ushort* __restrict__ fl,
                                             float* __restrict__ out) {
  const int t = threadIdx.x, lane = t & 63;
  const int wave = t >> 6, wm = wave >> 1, wn = wave & 1;
  const int bm = blockIdx.y << 7, bn = blockIdx.x << 7;
  const int hi = lane >> 4, r16 = lane & 15;
  short8 ah[4], al[4], bh[4], bl[4];
#pragma unroll
  for (int mi = 0; mi < 4; ++mi) {
    int row = bm + (wm << 6) + (mi << 4) + r16;
    ah[mi] = *(const short8*)(fh + (size_t)row * 32 + (hi << 3));
    al[mi] = *(const short8*)(fl + (size_t)row * 32 + (hi << 3));
  }
#pragma unroll
  for (int ni = 0; ni < 4; ++ni) {
    int row = bn + (wn << 6) + (ni << 4) + r16;
    bh[ni] = *(const short8*)(fh + (size_t)row * 32 + (hi << 3));
    bl[ni] = *(const short8*)(fl + (size_t)row * 32 + (hi << 3));
  }
#pragma unroll
  for (int mi = 0; mi < 4; ++mi)
#pragma unroll
    for (int ni = 0; ni < 4; ++ni) {
      f32x4 acc;
#pragma unroll
      for (int r = 0; r < 4; ++r) acc[r] = 0.f;
      acc = __builtin_amdgcn_mfma_f32_16x16x32_bf16(ah[mi], bh[ni], acc, 0, 0, 0);
      acc = __builtin_amdgcn_mfma_f32_16x16x32_bf16(ah[mi], bl[ni], acc, 0, 0, 0);
      acc = __builtin_amdgcn_mfma_f32_16x16x32_bf16(al[mi], bh[ni], acc, 0, 0, 0);
#pragma unroll
      for (int r2 = 0; r2 < 4; ++r2) {
        int gm = bm + (wm << 6) + (mi << 4) + (hi << 2) + r2;
        int gn = bn + (wn << 6) + (ni << 4) + r16;
        out[(size_t)gm * N_ + gn] = acc[r2];
      }
    }
}

// ---------------------------------------------------------------------------
// bf16-split MFMA GEMM (GFN), 128x128 tile, BK=64, 4 waves, XOR-swizzled LDS,
// issue-early register double-buffer. EPI==2 also emits p-threshold bitmap.
// ---------------------------------------------------------------------------
template<int NA, int NB, int EPI>
__global__ __launch_bounds__(256, 2) void k_mfma(
    const ushort* __restrict__ A0, const ushort* __restrict__ A1,
    const ushort* __restrict__ B0, const ushort* __restrict__ B1,
    const float* __restrict__ bias, float* __restrict__ Cf,
    ushort* __restrict__ Oh, ushort* __restrict__ Ol, int Nn, int K,
    ushort* __restrict__ Pb) {
  constexpr int NOPS = NA + NB;
  __shared__ __align__(16) ushort lds[NOPS * 8192];
  const int t = threadIdx.x, lane = t & 63;
  const int wave = t >> 6, wm = wave >> 1, wn = wave & 1;
  const int bm = blockIdx.y << 7, bn = blockIdx.x << 7;
  const int hi = lane >> 4, r16 = lane & 15, rx = r16 & 7;
  const int srow = t >> 3, sslot = t & 7;

  const ushort* gsrc[4];
  int rb[4];
  {
    int no = 0;
    gsrc[no] = A0; rb[no] = bm; no++;
    if (NA > 1) { gsrc[no] = A1; rb[no] = bm; no++; }
    gsrc[no] = B0; rb[no] = bn; no++;
    if (NB > 1) { gsrc[no] = B1; rb[no] = bn; no++; }
  }

  f32x4 acc[4][4];
#pragma unroll
  for (int i = 0; i < 4; ++i)
#pragma unroll
    for (int j = 0; j < 4; ++j)
#pragma unroll
      for (int r = 0; r < 4; ++r) acc[i][j][r] = 0.f;

  short8 stg[NOPS][4];
#define LOADT(KT)                                                                      \
  {                                                                                    \
    _Pragma("unroll") for (int op = 0; op < NOPS; ++op)                                \
        _Pragma("unroll") for (int i = 0; i < 4; ++i) {                                \
      int row = (i << 5) + srow;                                                       \
      stg[op][i] = *(const short8*)(gsrc[op] + (size_t)(rb[op] + row) * K + (KT) +     \
                                    (sslot << 3));                                     \
    }                                                                                  \
  }

  LOADT(0);
  for (int kt = 0; kt < K; kt += 64) {
    __syncthreads();
#pragma unroll
    for (int op = 0; op < NOPS; ++op)
#pragma unroll
      for (int i = 0; i < 4; ++i) {
        int row = (i << 5) + srow;
        *(short8*)(&lds[op * 8192 + row * 64 + ((sslot ^ (row & 7)) << 3)]) = stg[op][i];
      }
    __syncthreads();
    if (kt + 64 < K) LOADT(kt + 64);
#pragma unroll
    for (int k0 = 0; k0 < 2; ++k0) {
      const int soff = (((k0 << 2) + hi) ^ rx) << 3;
      short8 af[NA][4], bf[NB][4];
#pragma unroll
      for (int mi = 0; mi < 4; ++mi) {
        int row = (wm << 6) + (mi << 4) + r16;
        af[0][mi] = *(const short8*)(&lds[row * 64 + soff]);
        if (NA > 1) af[1][mi] = *(const short8*)(&lds[8192 + row * 64 + soff]);
      }
#pragma unroll
      for (int ni = 0; ni < 4; ++ni) {
        int row = (wn << 6) + (ni << 4) + r16;
        bf[0][ni] = *(const short8*)(&lds[NA * 8192 + row * 64 + soff]);
        if (NB > 1) bf[1][ni] = *(const short8*)(&lds[(NA + 1) * 8192 + row * 64 + soff]);
      }
#pragma unroll
      for (int mi = 0; mi < 4; ++mi)
#pragma unroll
        for (int ni = 0; ni < 4; ++ni) {
          acc[mi][ni] = __builtin_amdgcn_mfma_f32_16x16x32_bf16(af[0][mi], bf[0][ni], acc[mi][ni], 0, 0, 0);
          if (NB > 1)
            acc[mi][ni] = __builtin_amdgcn_mfma_f32_16x16x32_bf16(af[0][mi], bf[1][ni], acc[mi][ni], 0, 0, 0);
          if (NA > 1)
            acc[mi][ni] = __builtin_amdgcn_mfma_f32_16x16x32_bf16(af[1][mi], bf[0][ni], acc[mi][ni], 0, 0, 0);
        }
    }
  }
#pragma unroll
  for (int mi = 0; mi < 4; ++mi)
#pragma unroll
    for (int ni = 0; ni < 4; ++ni) {
      const int gn = bn + (wn << 6) + (ni << 4) + r16;
      const float bv = bias[gn];
#pragma unroll
      for (int r2 = 0; r2 < 4; ++r2) {
        const int gm = bm + (wm << 6) + (mi << 4) + (hi << 2) + r2;
        float v = acc[mi][ni][r2] + bv;
        if (EPI == 1) {
          v = fmaxf(v, 0.f);
          ushort hh = f2bf(v);
          Oh[(size_t)gm * Nn + gn] = hh;
          Ol[(size_t)gm * Nn + gn] = f2bf(v - bf2f(hh));
        } else {
          Cf[(size_t)gm * Nn + gn] = v;
          float p = rintf(fminf(fmaxf(v, 0.f), 1.f) + 0.1f);
          unsigned long long mask = __ballot(p != 0.f);
          if (r16 == 0)
            Pb[(size_t)gm * 256 + (gn >> 4)] = (ushort)(mask >> (hi << 4));
        }
      }
    }
#undef LOADT
}

// ---------------------------------------------------------------------------
extern "C" void kernel_launch(void* const* d_in, const int* in_sizes, int n_in,
                              void* d_out, int out_size, void* d_ws, size_t ws_size,
                              hipStream_t stream) {
  const float* data[3] = {(const float*)d_in[0], (const float*)d_in[1], (const float*)d_in[2]};
  const int D[3] = {512, 256, 128};
  const int* src[3] = {(const int*)d_in[3], (const int*)d_in[6], (const int*)d_in[9]};
  const int* dst[3] = {(const int*)d_in[4], (const int*)d_in[7], (const int*)d_in[10]};
  const float* w0[3] = {(const float*)d_in[12], (const float*)d_in[16], (const float*)d_in[20]};
  const float* b0[3] = {(const float*)d_in[13], (const float*)d_in[17], (const float*)d_in[21]};
  const float* w1[3] = {(const float*)d_in[14], (const float*)d_in[18], (const float*)d_in[22]};
  const float* b1[3] = {(const float*)d_in[15], (const float*)d_in[19], (const float*)d_in[23]};
  const float* wm0 = (const float*)d_in[24];
  const float* bm0 = (const float*)d_in[25];
  const float* wm1 = (const float*)d_in[26];
  const float* bm1 = (const float*)d_in[27];
  const float* fw[3] = {(const float*)d_in[28], (const float*)d_in[29], (const float*)d_in[30]};
  const float* gw1 = (const float*)d_in[31];
  const float* gb1 = (const float*)d_in[32];
  const float* gw2 = (const float*)d_in[33];
  const float* gb2 = (const float*)d_in[34];

  float* outf = (float*)d_out;
  float* adj_r = outf;                  // output 0
  float* adj_rec = outf + 16777216;     // output 1
  float* feat = outf + 33554432;        // output 2
  // adj_r region overlay (dead before G2 writes adj_r):
  ushort* w1h = (ushort*)outf;          // [2048,4096]
  ushort* w1l = w1h + 8388608;
  ushort* adjin = w1h + 16777216;       // [4096,4096]
  // adj_rec region overlay:
  ushort* o1u = (ushort*)adj_rec;
  ushort* h1h = o1u;                    // [4096,2048]  (dead after G2)
  ushort* h1l = o1u + 8388608;
  ushort* w2h = o1u + 16777216;         // [4096,2048]  (dead after G2)
  ushort* w2l = o1u + 25165824;
  ushort* Ab = o1u;                     // A bf16, written by buildA2 (h1 dead)
  float* SCR = outf + 25165824;         // 8.4M floats free after G2 until k_rec
  float* hbuf3 = SCR;                   // [4096,384]
  float* t2c = SCR + 1572864;           // [4096,192]
  float* part = SCR + 2359296;          // [8][4096][64] (reused for [..][32])

  float* wsf = (float*)d_ws;
  float* degA = wsf + 24576;
  unsigned* bmp = (unsigned*)(wsf + 28672);     // phase a only
  ushort* pb = (ushort*)(wsf + 28672);          // G2 threshold bitmap (2MB)
  float* hX3 = wsf + 28672;                     // [4096,384] (after buildA2)
  float* fvI = wsf + 28672;                     // [4096,192] (after agg128 done)
  float* zpre = wsf + 815104;
  float* zb = wsf + 1077248;
  float* t0 = wsf + 1339392;                    // [4096,64]
  ushort* hT0h = (ushort*)(wsf + 28672);        // [64][4096]
  ushort* hT0l = (ushort*)(wsf + 159744);
  float* h1c = wsf + 290816;                    // [4096,64]
  float* t1 = wsf + 552960;                     // [4096,32]
  ushort* hT1h = (ushort*)(wsf + 28672);        // [32][4096]
  ushort* hT1l = (ushort*)(wsf + 94208);
  ushort* fh = (ushort*)(wsf + 159744);         // [4096,32]
  ushort* fl = (ushort*)(wsf + 225280);
  int* csr = (int*)(wsf + 2125824);
  ushort* WT = (ushort*)(wsf + 2347264);        // transposed/split weights

  const int o_w0h[3] = {0, 131072, 196608}, o_w0l[3] = {65536, 163840, 212992};
  const int o_w1h[3] = {229376, 245760, 262144}, o_w1l[3] = {237568, 253952, 270336};
  const int o_fwh = 278528, o_fwl = 290816;
  const int o_m0h = 303104, o_m0l = 307200, o_m1h = 311296, o_m1l = 313344;

  // ---- phase (a): GFN ----
  hipMemsetAsync(wsf, 0, (size_t)1601536 * 4, stream);  // degs + degA + bitmaps
  k_edges<<<768, 256, 0, stream>>>(src[0], dst[0], src[1], dst[1], src[2], dst[2], wsf, bmp);
  k_prep<<<24576, 256, 0, stream>>>(bmp, adjin, (const float4*)gw1, (const float4*)gw2,
                                    w1h, w1l, w2h, w2l);
  {
    WArgs wa;
    for (int v = 0; v < 3; ++v) {
      wa.s[v] = {w0[v], WT + o_w0h[v], WT + o_w0l[v], D[v], 128, 7, D[v], 0};
      wa.s[3 + v] = {w1[v], WT + o_w1h[v], WT + o_w1l[v], 128, 64, 6, 128, 0};
      wa.s[6 + v] = {fw[v], WT + o_fwh, WT + o_fwl, 64, 64, 6, 192, v * 64};
    }
    wa.s[9] = {wm0, WT + o_m0h, WT + o_m0l, 64, 64, 6, 64, 0};
    wa.s[10] = {wm1, WT + o_m1h, WT + o_m1l, 64, 32, 5, 64, 0};
    k_wprep<<<dim3(32, 11), 256, 0, stream>>>(wa);
  }
  k_mfma<1, 2, 1><<<dim3(16, 32), 256, 0, stream>>>(
      adjin, nullptr, w1h, w1l, gb1, nullptr, h1h, h1l, 2048, 4096, nullptr);
  k_mfma<2, 2, 2><<<dim3(32, 32), 256, 0, stream>>>(
      h1h, h1l, w2h, w2l, gb2, adj_r, nullptr, nullptr, 4096, 2048, pb);
  k_buildA2<<<dim3(64, 64), 256, 0, stream>>>(pb, Ab, degA);

  // ---- phase (b): CSR + per-view stacks + fusion ----
  k_scan7<<<7, 256, 0, stream>>>(wsf, csr);
  k_fill<<<768, 256, 0, stream>>>(src[0], dst[0], src[1], dst[1], src[2], dst[2], csr);
  {
    GArgs g0;
    for (int v = 0; v < 3; ++v)
      g0.s[v] = {data[v], WT + o_w0h[v], WT + o_w0l[v], hX3 + v * 128,
                 wsf + v * 8192, D[v], 384, D[v]};
    k_gemms<128, 3><<<dim3(32, 3), 256, 0, stream>>>(g0);
  }
  {
    AB ab = {{b0[0], b0[1], b0[2]}};
    k_agg3<128, 1><<<dim3(1024, 3), 256, 0, stream>>>(hX3, 384, csr, wsf, ab, hbuf3, 384);
  }
  {
    GArgs g1;
    for (int v = 0; v < 3; ++v)
      g1.s[v] = {hbuf3 + v * 128, WT + o_w1h[v], WT + o_w1l[v], t2c + v * 64,
                 wsf + v * 8192, 384, 192, 128};
    k_gemms<64, 3><<<dim3(32, 3), 256, 0, stream>>>(g1);
  }
  {
    AB ab = {{b1[0], b1[1], b1[2]}};
    k_agg3<64, 0><<<dim3(1024, 3), 256, 0, stream>>>(t2c, 192, csr, wsf, ab, fvI, 192);
  }
  {
    GArgs gf;
    gf.s[0] = {fvI, WT + o_fwh, WT + o_fwl, zpre, nullptr, 192, 64, 192};
    k_gemms<64, 1><<<dim3(32, 1), 256, 0, stream>>>(gf);
  }
  k_softmax<<<1024, 256, 0, stream>>>(zpre, zb);

  // ---- phase (c): consensus GraphConvs (MFMA) + adj_rec ----
  {
    GArgs gm;
    gm.s[0] = {zb, WT + o_m0h, WT + o_m0l, t0, degA, 64, 64, 64};
    k_gemms<64, 1><<<dim3(32, 1), 256, 0, stream>>>(gm);
  }
  k_tsplit<64><<<64, 256, 0, stream>>>(t0, hT0h, hT0l);
  k_aggm<64><<<dim3(32, 8), 256, 0, stream>>>(Ab, hT0h, hT0l, part);
  k_fincons<64, 1, 0><<<1024, 256, 0, stream>>>(part, degA, bm0, h1c, nullptr, nullptr);
  {
    GArgs gm;
    gm.s[0] = {h1c, WT + o_m1h, WT + o_m1l, t1, degA, 64, 32, 64};
    k_gemms<32, 1><<<dim3(32, 1), 256, 0, stream>>>(gm);
  }
  k_tsplit<32><<<64, 256, 0, stream>>>(t1, hT1h, hT1l);
  k_aggm<32><<<dim3(32, 8), 256, 0, stream>>>(Ab, hT1h, hT1l, part);
  k_fincons<32, 0, 1><<<512, 256, 0, stream>>>(part, degA, bm1, feat, fh, fl);
  k_rec<<<dim3(32, 32), 256, 0, stream>>>(fh, fl, adj_rec);
}